// Round 1
// baseline (1052.223 us; speedup 1.0000x reference)
//
#include <hip/hip_runtime.h>

#define BATCH 2
#define CH    64
#define HH    64
#define WW    64
#define PIX   4096   // H*W
#define KTOP  8

// ---------- ws float layout ----------
// nk        : [BATCH*PIX]            @ 0
// kk        : [BATCH*PIX]            @ 8192
// cand_cost : [BATCH*PIX*32]         @ 16384
// cand_idx  : [BATCH*PIX*32] (int)   @ 16384 + 262144
// total = 540672 floats = 2.07 MB

__device__ __forceinline__ bool lessCI(float c1, int i1, float c2, int i2) {
  return c1 < c2 || (c1 == c2 && i1 < i2);
}

// Sorted-ascending top-K (smallest cost first). Fully static indexing:
// replace-last + unrolled bubble toward front. Ties break to lower index
// (matches jax.lax.top_k stability).
__device__ __forceinline__ void topk_insert(float (&c8)[KTOP], int (&i8)[KTOP],
                                            float cost, int jg) {
  if (lessCI(cost, jg, c8[KTOP - 1], i8[KTOP - 1])) {
    c8[KTOP - 1] = cost; i8[KTOP - 1] = jg;
#pragma unroll
    for (int p = KTOP - 1; p > 0; --p) {
      bool sw = lessCI(c8[p], i8[p], c8[p - 1], i8[p - 1]);
      float cl = sw ? c8[p] : c8[p - 1];
      float cgh = sw ? c8[p - 1] : c8[p];
      int   il = sw ? i8[p] : i8[p - 1];
      int   ih = sw ? i8[p - 1] : i8[p];
      c8[p - 1] = cl; c8[p] = cgh; i8[p - 1] = il; i8[p] = ih;
    }
  }
}

// ---------------- kernel 1: per-pixel k-norm ----------------
__global__ void nk_kernel(const float* __restrict__ k, float* __restrict__ nk) {
  int p = blockIdx.x * blockDim.x + threadIdx.x;   // 0..8191
  int b = p >> 12, pix = p & 4095;
  const float* kb = k + (size_t)b * (CH * PIX) + pix;
  float s = 0.f;
#pragma unroll
  for (int c = 0; c < CH; ++c) {
    float t = kb[c * PIX];
    s += t * t;
  }
  nk[p] = s;
}

// ---------------- kernel 2: 3x3 zero-padded stencil -> kk ----------------
__global__ void kk_kernel(const float* __restrict__ nk, float* __restrict__ kk) {
  int p = blockIdx.x * blockDim.x + threadIdx.x;
  int b = p >> 12, pix = p & 4095;
  int y = pix >> 6, x = pix & 63;
  float s = 0.f;
#pragma unroll
  for (int di = -1; di <= 1; ++di) {
#pragma unroll
    for (int dj = -1; dj <= 1; ++dj) {
      int yy = y + di, xx = x + dj;
      if ((unsigned)yy < (unsigned)HH && (unsigned)xx < (unsigned)WW)
        s += nk[(b << 12) + (yy << 6) + xx];
    }
  }
  kk[p] = s;
}

// ---------------- kernel 3: fused cost tile + per-quarter top-8 ----------------
// grid 512 = B(2) * iy(64) * quarter(4); block 256.
// Query tile = image row iy (64 pixels). Key quarter = 16 image rows.
// Per key row: 9 shift passes, each staging A[c][x]=q[c,iy+di,x+dj],
// B[c][jx]=k[c,jy+di,jx+dj] (zero-padded) and accumulating a 64x64x64 fp32
// outer-product (4x4 micro-tile per thread, float4 LDS reads).
__launch_bounds__(256, 2)
__global__ void cost_topk_kernel(const float* __restrict__ q,
                                 const float* __restrict__ k,
                                 const float* __restrict__ kkg,
                                 float* __restrict__ cand_cost,
                                 int* __restrict__ cand_idx) {
  __shared__ float At[CH][WW];       // [c][query x]
  __shared__ float Bt[CH][WW];       // [c][key x]
  __shared__ float Ct[WW][WW + 1];   // dot tile, padded (+1) for scan reads
  __shared__ float kkrow[WW];

  int bid = blockIdx.x;
  int b   = bid >> 8;
  int rem = bid & 255;
  int iy  = rem >> 2;
  int qtr = rem & 3;

  int tid = threadIdx.x;
  int tx = tid & 15, ty = tid >> 4;      // micro-tile coords
  int sr = tid & 63, sseg = tid >> 6;    // scan coords: row, 16-col segment

  const float* qb = q + (size_t)b * (CH * PIX);
  const float* kb = k + (size_t)b * (CH * PIX);

  float c8[KTOP]; int i8[KTOP];
#pragma unroll
  for (int s = 0; s < KTOP; ++s) { c8[s] = __builtin_inff(); i8[s] = 0x7fffffff; }

  for (int jt = 0; jt < 16; ++jt) {
    int jy = qtr * 16 + jt;

    float acc[4][4];
#pragma unroll
    for (int a = 0; a < 4; ++a)
#pragma unroll
      for (int bb = 0; bb < 4; ++bb) acc[a][bb] = 0.f;

    for (int d = 0; d < 9; ++d) {
      int di = d / 3 - 1, dj = d % 3 - 1;
      int qy = iy + di, ky = jy + di;
      __syncthreads();   // previous readers of At/Bt done
#pragma unroll
      for (int e = 0; e < 16; ++e) {
        int idx = e * 256 + tid;
        int c = idx >> 6, x = idx & 63;
        int gx = x + dj;
        float av = 0.f, bv = 0.f;
        if ((unsigned)gx < 64u) {
          if ((unsigned)qy < 64u) av = qb[(c << 12) + (qy << 6) + gx];
          if ((unsigned)ky < 64u) bv = kb[(c << 12) + (ky << 6) + gx];
        }
        At[c][x] = av;
        Bt[c][x] = bv;
      }
      __syncthreads();
#pragma unroll 8
      for (int c = 0; c < CH; ++c) {
        float4 a4 = *(const float4*)&At[c][ty * 4];
        float4 b4 = *(const float4*)&Bt[c][tx * 4];
        float av[4] = {a4.x, a4.y, a4.z, a4.w};
        float bvv[4] = {b4.x, b4.y, b4.z, b4.w};
#pragma unroll
        for (int a = 0; a < 4; ++a)
#pragma unroll
          for (int bb = 0; bb < 4; ++bb) acc[a][bb] += av[a] * bvv[bb];
      }
    }

    // publish dot tile + kk row, then fused top-8 scan
#pragma unroll
    for (int a = 0; a < 4; ++a)
#pragma unroll
      for (int bb = 0; bb < 4; ++bb)
        Ct[ty * 4 + a][tx * 4 + bb] = acc[a][bb];
    if (tid < 64) kkrow[tid] = kkg[(b << 12) + (jy << 6) + tid];
    __syncthreads();

#pragma unroll
    for (int jj = 0; jj < 16; ++jj) {
      int jl = sseg * 16 + jj;
      float cost = kkrow[jl] - 2.f * Ct[sr][jl];
      int jg = (jy << 6) + jl;
      topk_insert(c8, i8, cost, jg);
    }
  }

  // merge 4 segments per row -> per-quarter top-8 -> ws
  __syncthreads();
  float* candC = &At[0][0];       // reuse: 64 rows x 32 entries
  int*   candI = (int*)&Bt[0][0];
#pragma unroll
  for (int s = 0; s < KTOP; ++s) {
    candC[sr * 32 + sseg * 8 + s] = c8[s];
    candI[sr * 32 + sseg * 8 + s] = i8[s];
  }
  __syncthreads();
  if (tid < 64) {
    float f8[KTOP]; int g8[KTOP];
#pragma unroll
    for (int s = 0; s < KTOP; ++s) { f8[s] = __builtin_inff(); g8[s] = 0x7fffffff; }
    for (int t2 = 0; t2 < 32; ++t2)
      topk_insert(f8, g8, candC[tid * 32 + t2], candI[tid * 32 + t2]);
    int i = (b << 12) + (iy << 6) + tid;
#pragma unroll
    for (int s = 0; s < KTOP; ++s) {
      cand_cost[i * 32 + qtr * 8 + s] = f8[s];
      cand_idx [i * 32 + qtr * 8 + s] = g8[s];
    }
  }
}

// ---------------- kernel 4: merge quarters, softmax, gather v ----------------
// grid 128 = B * iy; block 256 (4 channels x 64 pixels per pass)
__global__ void merge_out_kernel(const float* __restrict__ cand_cost,
                                 const int* __restrict__ cand_idx,
                                 const float* __restrict__ v,
                                 float* __restrict__ out) {
  __shared__ float wL[64][9];
  __shared__ int   idL[64][9];
  int bid = blockIdx.x;
  int b = bid >> 6, iy = bid & 63;
  int tid = threadIdx.x;

  if (tid < 64) {
    int i = (b << 12) + (iy << 6) + tid;
    float c8[KTOP]; int i8[KTOP];
#pragma unroll
    for (int s = 0; s < KTOP; ++s) { c8[s] = __builtin_inff(); i8[s] = 0x7fffffff; }
    for (int t2 = 0; t2 < 32; ++t2)
      topk_insert(c8, i8, cand_cost[i * 32 + t2], cand_idx[i * 32 + t2]);
    float m = c8[0];       // sorted ascending -> min first
    float w[KTOP], wsum = 0.f;
#pragma unroll
    for (int s = 0; s < KTOP; ++s) { w[s] = __expf(m - c8[s]); wsum += w[s]; }
    float inv = 1.f / wsum;
#pragma unroll
    for (int s = 0; s < KTOP; ++s) { wL[tid][s] = w[s] * inv; idL[tid][s] = i8[s]; }
  }
  __syncthreads();

  int x = tid & 63, cq = tid >> 6;
  float w[KTOP]; int id[KTOP];
#pragma unroll
  for (int s = 0; s < KTOP; ++s) { w[s] = wL[x][s]; id[s] = idL[x][s]; }
  const float* vb = v + (size_t)b * (CH * PIX);
  float* ob = out + (size_t)b * (CH * PIX);
#pragma unroll 4
  for (int cc = 0; cc < 16; ++cc) {
    int c = cc * 4 + cq;
    const float* vc = vb + c * PIX;
    float acc = 0.f;
#pragma unroll
    for (int s = 0; s < KTOP; ++s) acc += w[s] * vc[id[s]];
    ob[c * PIX + (iy << 6) + x] = acc;
  }
}

extern "C" void kernel_launch(void* const* d_in, const int* in_sizes, int n_in,
                              void* d_out, int out_size, void* d_ws, size_t ws_size,
                              hipStream_t stream) {
  const float* q = (const float*)d_in[0];
  const float* k = (const float*)d_in[1];
  const float* v = (const float*)d_in[2];
  float* out = (float*)d_out;

  float* ws        = (float*)d_ws;
  float* nk        = ws;
  float* kk        = ws + 8192;
  float* cand_cost = ws + 16384;
  int*   cand_idx  = (int*)(ws + 16384 + 262144);

  nk_kernel<<<32, 256, 0, stream>>>(k, nk);
  kk_kernel<<<32, 256, 0, stream>>>(nk, kk);
  cost_topk_kernel<<<512, 256, 0, stream>>>(q, k, kk, cand_cost, cand_idx);
  merge_out_kernel<<<128, 256, 0, stream>>>(cand_cost, cand_idx, v, out);
}

// Round 2
// 442.046 us; speedup vs baseline: 2.3803x; 2.3803x over previous
//
#include <hip/hip_runtime.h>

#define BATCH 2
#define CH    64
#define HH    64
#define WW    64
#define PIX   4096   // H*W
#define KTOP  8

// ---------- ws float layout ----------
// nk        : [BATCH*PIX]            @ 0
// kk        : [BATCH*PIX]            @ 8192
// cand_cost : [BATCH*PIX*32]         @ 16384
// cand_idx  : [BATCH*PIX*32] (int)   @ 16384 + 262144
// total = 540672 floats = 2.07 MB

__device__ __forceinline__ bool lessCI(float c1, int i1, float c2, int i2) {
  return c1 < c2 || (c1 == c2 && i1 < i2);
}

// Sorted-ascending top-K, fully static indexing (no scratch spill).
__device__ __forceinline__ void topk_insert(float (&c8)[KTOP], int (&i8)[KTOP],
                                            float cost, int jg) {
  if (lessCI(cost, jg, c8[KTOP - 1], i8[KTOP - 1])) {
    c8[KTOP - 1] = cost; i8[KTOP - 1] = jg;
#pragma unroll
    for (int p = KTOP - 1; p > 0; --p) {
      bool sw = lessCI(c8[p], i8[p], c8[p - 1], i8[p - 1]);
      float cl = sw ? c8[p] : c8[p - 1];
      float cgh = sw ? c8[p - 1] : c8[p];
      int   il = sw ? i8[p] : i8[p - 1];
      int   ih = sw ? i8[p - 1] : i8[p];
      c8[p - 1] = cl; c8[p] = cgh; i8[p - 1] = il; i8[p] = ih;
    }
  }
}

// ---------------- kernel 1: per-pixel k-norm ----------------
__global__ void nk_kernel(const float* __restrict__ k, float* __restrict__ nk) {
  int p = blockIdx.x * blockDim.x + threadIdx.x;   // 0..8191
  int b = p >> 12, pix = p & 4095;
  const float* kb = k + (size_t)b * (CH * PIX) + pix;
  float s = 0.f;
#pragma unroll
  for (int c = 0; c < CH; ++c) {
    float t = kb[c * PIX];
    s += t * t;
  }
  nk[p] = s;
}

// ---------------- kernel 2: 3x3 zero-padded stencil -> kk ----------------
__global__ void kk_kernel(const float* __restrict__ nk, float* __restrict__ kk) {
  int p = blockIdx.x * blockDim.x + threadIdx.x;
  int b = p >> 12, pix = p & 4095;
  int y = pix >> 6, x = pix & 63;
  float s = 0.f;
#pragma unroll
  for (int di = -1; di <= 1; ++di) {
#pragma unroll
    for (int dj = -1; dj <= 1; ++dj) {
      int yy = y + di, xx = x + dj;
      if ((unsigned)yy < (unsigned)HH && (unsigned)xx < (unsigned)WW)
        s += nk[(b << 12) + (yy << 6) + xx];
    }
  }
  kk[p] = s;
}

// ---------------- kernel 3: shared-shift cost + per-quarter top-8 ----------------
// Identity: patchdot(i,j) = sum_{d=-1..1} sum_{dj=-1..1} R_d[x+dj][jx+dj]
// where R_d = dot-tile between q row iy+d and k row jy+d (same row shift!).
// 3 GEMMs per (iy,jy) instead of 9; dj-shifts via a diagonal stencil on a
// zero-bordered LDS tile.
// grid 512 = B(2) * iy(64) * quarter(4); block 256; 1 block/CU (116 KB LDS).
__launch_bounds__(256, 1)
__global__ void cost_topk_kernel(const float* __restrict__ q,
                                 const float* __restrict__ k,
                                 const float* __restrict__ kkg,
                                 float* __restrict__ cand_cost,
                                 int* __restrict__ cand_idx) {
  __shared__ float Aq[3][CH][WW];   // q rows iy-1..iy+1, [d][c][x]   48 KB
  __shared__ float Bk[3][CH][WW];   // k row ring, slot=(row%3)       48 KB
  __shared__ float Rb[66][67];      // dot tile + zero border         17.7 KB
                                    // stride 67: bank=(3r+c)%32 -> <=2-way

  int bid = blockIdx.x;
  int b   = bid >> 8;
  int rem = bid & 255;
  int iy  = rem >> 2;
  int qtr = rem & 3;
  int q0  = qtr * 16;

  int tid = threadIdx.x;
  int tx = tid & 15, ty = tid >> 4;      // GEMM micro-tile coords (4x4)
  int sx = tid & 63, sseg = tid >> 6;    // stencil coords: query x, jx segment
  int jxs = sseg * 16;

  const float* qb = q + (size_t)b * (CH * PIX);
  const float* kb = k + (size_t)b * (CH * PIX);

  // zero Rb once; borders stay zero forever (interior overwritten each GEMM)
  for (int i = tid; i < 66 * 67; i += 256) ((float*)Rb)[i] = 0.f;

  // stage q rows iy-1..iy+1 (zero tile if row OOB)
#pragma unroll
  for (int d = 0; d < 3; ++d) {
    int qy = iy - 1 + d;
    bool ok = (unsigned)qy < 64u;
#pragma unroll
    for (int e = 0; e < 4; ++e) {
      int base = e * 1024 + tid * 4;
      int c = base >> 6, x = base & 63;
      float4 v = make_float4(0.f, 0.f, 0.f, 0.f);
      if (ok) v = *(const float4*)&qb[(c << 12) + (qy << 6) + x];
      *(float4*)&Aq[d][c][x] = v;
    }
  }
  // stage k rows q0-1..q0+1 into ring
  for (int r = q0 - 1; r <= q0 + 1; ++r) {
    int slot = (r + 3) % 3;
    bool ok = (unsigned)r < 64u;
#pragma unroll
    for (int e = 0; e < 4; ++e) {
      int base = e * 1024 + tid * 4;
      int c = base >> 6, x = base & 63;
      float4 v = make_float4(0.f, 0.f, 0.f, 0.f);
      if (ok) v = *(const float4*)&kb[(c << 12) + (r << 6) + x];
      *(float4*)&Bk[slot][c][x] = v;
    }
  }
  __syncthreads();

  float c8[KTOP]; int i8[KTOP];
#pragma unroll
  for (int s = 0; s < KTOP; ++s) { c8[s] = __builtin_inff(); i8[s] = 0x7fffffff; }

  for (int jt = 0; jt < 16; ++jt) {
    int jy = q0 + jt;

    // --- register-prefetch k row jy+2 (consumed next step, slot (jy+2)%3) ---
    int pr = jy + 2;
    bool pwrite = (jt < 15);
    bool pok = pwrite && (pr < 64);
    float4 pf[4];
#pragma unroll
    for (int e = 0; e < 4; ++e) {
      int base = e * 1024 + tid * 4;
      int c = base >> 6, x = base & 63;
      pf[e] = make_float4(0.f, 0.f, 0.f, 0.f);
      if (pok) pf[e] = *(const float4*)&kb[(c << 12) + (pr << 6) + x];
    }

    float acc[16];
#pragma unroll
    for (int jj = 0; jj < 16; ++jj) acc[jj] = 0.f;

#pragma unroll
    for (int dd = 0; dd < 3; ++dd) {            // row shift d = dd-1
      int slot = (jy + dd - 1 + 3) % 3;
      const float(*At)[WW] = Aq[dd];
      const float(*Bt)[WW] = Bk[slot];

      float fr[4][4];
#pragma unroll
      for (int a = 0; a < 4; ++a)
#pragma unroll
        for (int bb = 0; bb < 4; ++bb) fr[a][bb] = 0.f;

#pragma unroll 8
      for (int c = 0; c < CH; ++c) {
        float4 a4 = *(const float4*)&At[c][ty * 4];
        float4 b4 = *(const float4*)&Bt[c][tx * 4];
        float av[4] = {a4.x, a4.y, a4.z, a4.w};
        float bv[4] = {b4.x, b4.y, b4.z, b4.w};
#pragma unroll
        for (int a = 0; a < 4; ++a)
#pragma unroll
          for (int bb = 0; bb < 4; ++bb) fr[a][bb] += av[a] * bv[bb];
      }

      __syncthreads();   // all waves done reading Rb (and, at dd=0, Bk slot (jy-1)%3)

      // write dot tile into bordered Rb
#pragma unroll
      for (int a = 0; a < 4; ++a)
#pragma unroll
        for (int bb = 0; bb < 4; ++bb)
          Rb[ty * 4 + a + 1][tx * 4 + bb + 1] = fr[a][bb];

      if (dd == 0 && pwrite) {
        int slotw = pr % 3;   // == (jy-1)%3, fully consumed at dd=0
#pragma unroll
        for (int e = 0; e < 4; ++e) {
          int base = e * 1024 + tid * 4;
          int c = base >> 6, x = base & 63;
          *(float4*)&Bk[slotw][c][x] = pf[e];
        }
      }

      __syncthreads();   // Rb tile visible

      // diagonal 3-point stencil: acc[jj] += Rb[sx+dj][jxs+jj+dj] (border=0)
      int xr = sx + 1;
#pragma unroll
      for (int dj = -1; dj <= 1; ++dj) {
        const float* row = &Rb[xr + dj][jxs + dj + 1];
#pragma unroll
        for (int jj = 0; jj < 16; ++jj) acc[jj] += row[jj];
      }
    }

    // cost + fused top-8 (kk read is wave-uniform -> scalar loads)
    const float* kkr = kkg + (b << 12) + (jy << 6) + jxs;
#pragma unroll
    for (int jj = 0; jj < 16; ++jj) {
      float cost = kkr[jj] - 2.f * acc[jj];
      topk_insert(c8, i8, cost, (jy << 6) + jxs + jj);
    }
  }

  // merge 4 segments per query pixel -> per-quarter top-8 -> ws
  __syncthreads();
  float* candC = (float*)Aq;      // reuse LDS: 64 px x 32 entries
  int*   candI = (int*)Bk;
#pragma unroll
  for (int s = 0; s < KTOP; ++s) {
    candC[sx * 32 + sseg * 8 + s] = c8[s];
    candI[sx * 32 + sseg * 8 + s] = i8[s];
  }
  __syncthreads();
  if (tid < 64) {
    float f8[KTOP]; int g8[KTOP];
#pragma unroll
    for (int s = 0; s < KTOP; ++s) { f8[s] = __builtin_inff(); g8[s] = 0x7fffffff; }
    for (int t2 = 0; t2 < 32; ++t2)
      topk_insert(f8, g8, candC[tid * 32 + t2], candI[tid * 32 + t2]);
    int i = (b << 12) + (iy << 6) + tid;
#pragma unroll
    for (int s = 0; s < KTOP; ++s) {
      cand_cost[i * 32 + qtr * 8 + s] = f8[s];
      cand_idx [i * 32 + qtr * 8 + s] = g8[s];
    }
  }
}

// ---------------- kernel 4: merge quarters, softmax, gather v ----------------
__global__ void merge_out_kernel(const float* __restrict__ cand_cost,
                                 const int* __restrict__ cand_idx,
                                 const float* __restrict__ v,
                                 float* __restrict__ out) {
  __shared__ float wL[64][9];
  __shared__ int   idL[64][9];
  int bid = blockIdx.x;
  int b = bid >> 6, iy = bid & 63;
  int tid = threadIdx.x;

  if (tid < 64) {
    int i = (b << 12) + (iy << 6) + tid;
    float c8[KTOP]; int i8[KTOP];
#pragma unroll
    for (int s = 0; s < KTOP; ++s) { c8[s] = __builtin_inff(); i8[s] = 0x7fffffff; }
    for (int t2 = 0; t2 < 32; ++t2)
      topk_insert(c8, i8, cand_cost[i * 32 + t2], cand_idx[i * 32 + t2]);
    float m = c8[0];
    float w[KTOP], wsum = 0.f;
#pragma unroll
    for (int s = 0; s < KTOP; ++s) { w[s] = __expf(m - c8[s]); wsum += w[s]; }
    float inv = 1.f / wsum;
#pragma unroll
    for (int s = 0; s < KTOP; ++s) { wL[tid][s] = w[s] * inv; idL[tid][s] = i8[s]; }
  }
  __syncthreads();

  int x = tid & 63, cq = tid >> 6;
  float w[KTOP]; int id[KTOP];
#pragma unroll
  for (int s = 0; s < KTOP; ++s) { w[s] = wL[x][s]; id[s] = idL[x][s]; }
  const float* vb = v + (size_t)b * (CH * PIX);
  float* ob = out + (size_t)b * (CH * PIX);
#pragma unroll 4
  for (int cc = 0; cc < 16; ++cc) {
    int c = cc * 4 + cq;
    const float* vc = vb + c * PIX;
    float acc = 0.f;
#pragma unroll
    for (int s = 0; s < KTOP; ++s) acc += w[s] * vc[id[s]];
    ob[c * PIX + (iy << 6) + x] = acc;
  }
}

extern "C" void kernel_launch(void* const* d_in, const int* in_sizes, int n_in,
                              void* d_out, int out_size, void* d_ws, size_t ws_size,
                              hipStream_t stream) {
  const float* q = (const float*)d_in[0];
  const float* k = (const float*)d_in[1];
  const float* v = (const float*)d_in[2];
  float* out = (float*)d_out;

  float* ws        = (float*)d_ws;
  float* nk        = ws;
  float* kk        = ws + 8192;
  float* cand_cost = ws + 16384;
  int*   cand_idx  = (int*)(ws + 16384 + 262144);

  nk_kernel<<<32, 256, 0, stream>>>(k, nk);
  kk_kernel<<<32, 256, 0, stream>>>(nk, kk);
  cost_topk_kernel<<<512, 256, 0, stream>>>(q, k, kk, cand_cost, cand_idx);
  merge_out_kernel<<<128, 256, 0, stream>>>(cand_cost, cand_idx, v, out);
}

// Round 3
// 160.890 us; speedup vs baseline: 6.5400x; 2.7475x over previous
//
#include <hip/hip_runtime.h>

#define BATCH 2
#define CH    64
#define HH    64
#define WW    64
#define PIX   4096   // H*W
#define KTOP  8

typedef unsigned short u16;
typedef short bf16x8 __attribute__((ext_vector_type(8)));   // 8 bf16 = 4 VGPR
typedef float f32x16 __attribute__((ext_vector_type(16)));  // 32x32 acc

// ---------- ws float layout ----------
// nk        : [BATCH*PIX]            @ 0
// kk        : [BATCH*PIX]            @ 8192
// cand_cost : [BATCH*PIX*32]         @ 16384
// cand_idx  : [BATCH*PIX*32] (int)   @ 16384 + 262144

__device__ __forceinline__ bool lessCI(float c1, int i1, float c2, int i2) {
  return c1 < c2 || (c1 == c2 && i1 < i2);
}

__device__ __forceinline__ void topk_insert(float (&c8)[KTOP], int (&i8)[KTOP],
                                            float cost, int jg) {
  if (lessCI(cost, jg, c8[KTOP - 1], i8[KTOP - 1])) {
    c8[KTOP - 1] = cost; i8[KTOP - 1] = jg;
#pragma unroll
    for (int p = KTOP - 1; p > 0; --p) {
      bool sw = lessCI(c8[p], i8[p], c8[p - 1], i8[p - 1]);
      float cl = sw ? c8[p] : c8[p - 1];
      float cgh = sw ? c8[p - 1] : c8[p];
      int   il = sw ? i8[p] : i8[p - 1];
      int   ih = sw ? i8[p - 1] : i8[p];
      c8[p - 1] = cl; c8[p] = cgh; i8[p - 1] = il; i8[p] = ih;
    }
  }
}

__device__ __forceinline__ u16 f2bf(float x) {
  unsigned u = __builtin_bit_cast(unsigned, x);
  unsigned r = u + 0x7fffu + ((u >> 16) & 1u);   // RNE truncate
  return (u16)(r >> 16);
}
__device__ __forceinline__ float bf2f(u16 h) {
  unsigned u = ((unsigned)h) << 16;
  return __builtin_bit_cast(float, u);
}

// convert 16 fp32 (ch group g, pixel pix) -> hi/lo bf16, write swizzled LDS
__device__ __forceinline__ void cvt_write16(u16* hiD, u16* loD, int pix, int g,
                                            const float (&pv)[16]) {
  u16 hi[16], lo[16];
#pragma unroll
  for (int e = 0; e < 16; ++e) {
    u16 h = f2bf(pv[e]);
    hi[e] = h;
    lo[e] = f2bf(pv[e] - bf2f(h));
  }
  int sw = (pix & 7) << 3;
#pragma unroll
  for (int c = 0; c < 2; ++c) {
    int idx = ((pix << 6) + (g << 4) + (c << 3)) ^ sw;   // 8-aligned, 16B
    uint4 wh, wl;
    wh.x = (unsigned)hi[c*8+0] | ((unsigned)hi[c*8+1] << 16);
    wh.y = (unsigned)hi[c*8+2] | ((unsigned)hi[c*8+3] << 16);
    wh.z = (unsigned)hi[c*8+4] | ((unsigned)hi[c*8+5] << 16);
    wh.w = (unsigned)hi[c*8+6] | ((unsigned)hi[c*8+7] << 16);
    wl.x = (unsigned)lo[c*8+0] | ((unsigned)lo[c*8+1] << 16);
    wl.y = (unsigned)lo[c*8+2] | ((unsigned)lo[c*8+3] << 16);
    wl.z = (unsigned)lo[c*8+4] | ((unsigned)lo[c*8+5] << 16);
    wl.w = (unsigned)lo[c*8+6] | ((unsigned)lo[c*8+7] << 16);
    *(uint4*)&hiD[idx] = wh;
    *(uint4*)&loD[idx] = wl;
  }
}

// ---------------- kernel 1: per-pixel k-norm (fp32, exact) ----------------
__global__ void nk_kernel(const float* __restrict__ k, float* __restrict__ nk) {
  int p = blockIdx.x * blockDim.x + threadIdx.x;
  int b = p >> 12, pix = p & 4095;
  const float* kb = k + (size_t)b * (CH * PIX) + pix;
  float s = 0.f;
#pragma unroll
  for (int c = 0; c < CH; ++c) { float t = kb[c * PIX]; s += t * t; }
  nk[p] = s;
}

// ---------------- kernel 2: 3x3 zero-padded stencil -> kk ----------------
__global__ void kk_kernel(const float* __restrict__ nk, float* __restrict__ kk) {
  int p = blockIdx.x * blockDim.x + threadIdx.x;
  int b = p >> 12, pix = p & 4095;
  int y = pix >> 6, x = pix & 63;
  float s = 0.f;
#pragma unroll
  for (int di = -1; di <= 1; ++di)
#pragma unroll
    for (int dj = -1; dj <= 1; ++dj) {
      int yy = y + di, xx = x + dj;
      if ((unsigned)yy < 64u && (unsigned)xx < 64u)
        s += nk[(b << 12) + (yy << 6) + xx];
    }
  kk[p] = s;
}

// ---------------- kernel 3: MFMA cost + per-quarter top-8 ----------------
// S[x][jx] = sum_d q_{iy+d}(x) . k_{jy+d}(jx)  via one K=576 bf16 hi/lo GEMM
// cost[x][jx] = kk[jy][jx'] - 2 * sum_dj S[x+dj][jx+dj]  (zero-bordered Rb)
// grid 512 = B*iy*quarter; block 256 (4 waves = 4 32x32 quadrants); 2 blocks/CU.
__launch_bounds__(256, 2)
__global__ void cost_topk_kernel(const float* __restrict__ q,
                                 const float* __restrict__ k,
                                 const float* __restrict__ kkg,
                                 float* __restrict__ cand_cost,
                                 int* __restrict__ cand_idx) {
  __shared__ u16  ringH[3][PIX];     // k-row ring, bf16 hi, [pix][ch] swizzled
  __shared__ u16  ringL[3][PIX];     // bf16 lo                       48 KB tot
  __shared__ float Rb[66][67];       // S tile + zero border          17.3 KB

  int bid = blockIdx.x;
  int b   = bid >> 8;
  int rem = bid & 255;
  int iy  = rem >> 2;
  int qtr = rem & 3;
  int q0  = qtr * 16;

  int tid  = threadIdx.x;
  int lane = tid & 63, wv = tid >> 6;
  int wr = wv >> 1, wc = wv & 1;          // quadrant of the 64x64 tile
  int l31 = lane & 31, lk8 = (lane >> 5) << 3;
  int apix = wr * 32 + l31;               // A row (query pixel)
  int bpix = wc * 32 + l31;               // B col (key pixel)
  int spix = tid & 63, sg = tid >> 6;     // staging coords
  int sx = tid & 63, sseg = tid >> 6;     // stencil coords
  int jxs = sseg * 16;

  const float* qb = q + (size_t)b * (CH * PIX);
  const float* kb = k + (size_t)b * (CH * PIX);

  // ---- prologue: stage q rows -> A fragments in registers ----
  u16* qsH = (u16*)Rb;          // reuse Rb as q staging (16 KB <= 17.3 KB)
  u16* qsL = qsH + PIX;
  bf16x8 qa[3][4], ql[3][4];
#pragma unroll
  for (int d = 0; d < 3; ++d) {
    int qy = iy - 1 + d;
    bool ok = (unsigned)qy < 64u;
    {
      float pv[16];
      const float* src = qb + (qy << 6) + spix;
#pragma unroll
      for (int e = 0; e < 16; ++e) pv[e] = ok ? src[((sg << 4) + e) << 12] : 0.f;
      cvt_write16(qsH, qsL, spix, sg, pv);
    }
    __syncthreads();
    int swA = (apix & 7) << 3;
#pragma unroll
    for (int c4 = 0; c4 < 4; ++c4) {
      int idx = ((apix << 6) + (c4 << 4) + lk8) ^ swA;
      qa[d][c4] = *(const bf16x8*)&qsH[idx];
      ql[d][c4] = *(const bf16x8*)&qsL[idx];
    }
    __syncthreads();
  }

  // zero Rb (borders stay zero); stage k rows q0-1..q0+1
  for (int i = tid; i < 66 * 67; i += 256) ((float*)Rb)[i] = 0.f;
  for (int r = q0 - 1; r <= q0 + 1; ++r) {
    int slot = (r + 3) % 3;
    bool ok = (unsigned)r < 64u;
    float pv[16];
    const float* src = kb + (r << 6) + spix;
#pragma unroll
    for (int e = 0; e < 16; ++e) pv[e] = ok ? src[((sg << 4) + e) << 12] : 0.f;
    cvt_write16(ringH[slot], ringL[slot], spix, sg, pv);
  }
  __syncthreads();

  float c8[KTOP]; int i8[KTOP];
#pragma unroll
  for (int s = 0; s < KTOP; ++s) { c8[s] = __builtin_inff(); i8[s] = 0x7fffffff; }

  int swB = (bpix & 7) << 3;

  for (int jt = 0; jt < 16; ++jt) {
    int jy = q0 + jt;

    // prefetch k row jy+2 into registers (LDS write after the barrier)
    float pv[16];
    bool pwrite = (jt < 15);
    {
      int pr = jy + 2;
      bool pok = pwrite && (pr < 64);
      const float* src = kb + (pr << 6) + spix;
#pragma unroll
      for (int e = 0; e < 16; ++e) pv[e] = pok ? src[((sg << 4) + e) << 12] : 0.f;
    }

    // ---- 36 MFMA: S quadrant, K = 3 rows x 4 ch-chunks x {hh, lh, hl} ----
    f32x16 acc;
#pragma unroll
    for (int i = 0; i < 16; ++i) acc[i] = 0.f;
#pragma unroll
    for (int d = 0; d < 3; ++d) {
      int slot = (jy + d + 2) % 3;
      const u16* rh = ringH[slot];
      const u16* rl = ringL[slot];
#pragma unroll
      for (int c4 = 0; c4 < 4; ++c4) {
        int idx = ((bpix << 6) + (c4 << 4) + lk8) ^ swB;
        bf16x8 bh = *(const bf16x8*)&rh[idx];
        bf16x8 bl = *(const bf16x8*)&rl[idx];
        acc = __builtin_amdgcn_mfma_f32_32x32x16_bf16(qa[d][c4], bh, acc, 0, 0, 0);
        acc = __builtin_amdgcn_mfma_f32_32x32x16_bf16(ql[d][c4], bh, acc, 0, 0, 0);
        acc = __builtin_amdgcn_mfma_f32_32x32x16_bf16(qa[d][c4], bl, acc, 0, 0, 0);
      }
    }

    __syncthreads();   // stencil readers of Rb done; ring slot (jy+2)%3 free

    // write S quadrant into bordered Rb (C/D: col=lane&31, row=(r&3)+8*(r>>2)+4*(lane>>5))
#pragma unroll
    for (int r = 0; r < 16; ++r) {
      int row = wr * 32 + (r & 3) + ((r >> 2) << 3) + ((lane >> 5) << 2);
      Rb[row + 1][wc * 32 + l31 + 1] = acc[r];
    }
    if (pwrite) cvt_write16(ringH[(jy + 2) % 3], ringL[(jy + 2) % 3], spix, sg, pv);

    __syncthreads();   // S visible

    // diagonal 3-point stencil + cost + fused top-8
    float a16[16];
#pragma unroll
    for (int jj = 0; jj < 16; ++jj) a16[jj] = 0.f;
    int xr = sx + 1;
#pragma unroll
    for (int dj = -1; dj <= 1; ++dj) {
      const float* row = &Rb[xr + dj][jxs + dj + 1];
#pragma unroll
      for (int jj = 0; jj < 16; ++jj) a16[jj] += row[jj];
    }
    const float* kkr = kkg + (b << 12) + (jy << 6) + jxs;   // wave-uniform
#pragma unroll
    for (int jj = 0; jj < 16; ++jj) {
      float cost = kkr[jj] - 2.f * a16[jj];
      topk_insert(c8, i8, cost, (jy << 6) + jxs + jj);
    }
  }

  // merge 4 segments per query pixel -> per-quarter top-8 -> ws
  __syncthreads();
  float* candC = (float*)ringH;
  int*   candI = (int*)ringL;
#pragma unroll
  for (int s = 0; s < KTOP; ++s) {
    candC[sx * 32 + sseg * 8 + s] = c8[s];
    candI[sx * 32 + sseg * 8 + s] = i8[s];
  }
  __syncthreads();
  if (tid < 64) {
    float f8[KTOP]; int g8[KTOP];
#pragma unroll
    for (int s = 0; s < KTOP; ++s) { f8[s] = __builtin_inff(); g8[s] = 0x7fffffff; }
    for (int t2 = 0; t2 < 32; ++t2)
      topk_insert(f8, g8, candC[tid * 32 + t2], candI[tid * 32 + t2]);
    int i = (b << 12) + (iy << 6) + tid;
#pragma unroll
    for (int s = 0; s < KTOP; ++s) {
      cand_cost[i * 32 + qtr * 8 + s] = f8[s];
      cand_idx [i * 32 + qtr * 8 + s] = g8[s];
    }
  }
}

// ---------------- kernel 4: merge quarters, softmax, gather v ----------------
__global__ void merge_out_kernel(const float* __restrict__ cand_cost,
                                 const int* __restrict__ cand_idx,
                                 const float* __restrict__ v,
                                 float* __restrict__ out) {
  __shared__ float wL[64][9];
  __shared__ int   idL[64][9];
  int bid = blockIdx.x;
  int b = bid >> 6, iy = bid & 63;
  int tid = threadIdx.x;

  if (tid < 64) {
    int i = (b << 12) + (iy << 6) + tid;
    float c8[KTOP]; int i8[KTOP];
#pragma unroll
    for (int s = 0; s < KTOP; ++s) { c8[s] = __builtin_inff(); i8[s] = 0x7fffffff; }
    for (int t2 = 0; t2 < 32; ++t2)
      topk_insert(c8, i8, cand_cost[i * 32 + t2], cand_idx[i * 32 + t2]);
    float m = c8[0];
    float w[KTOP], wsum = 0.f;
#pragma unroll
    for (int s = 0; s < KTOP; ++s) { w[s] = __expf(m - c8[s]); wsum += w[s]; }
    float inv = 1.f / wsum;
#pragma unroll
    for (int s = 0; s < KTOP; ++s) { wL[tid][s] = w[s] * inv; idL[tid][s] = i8[s]; }
  }
  __syncthreads();

  int x = tid & 63, cq = tid >> 6;
  float w[KTOP]; int id[KTOP];
#pragma unroll
  for (int s = 0; s < KTOP; ++s) { w[s] = wL[x][s]; id[s] = idL[x][s]; }
  const float* vb = v + (size_t)b * (CH * PIX);
  float* ob = out + (size_t)b * (CH * PIX);
#pragma unroll 4
  for (int cc = 0; cc < 16; ++cc) {
    int c = cc * 4 + cq;
    const float* vc = vb + c * PIX;
    float acc = 0.f;
#pragma unroll
    for (int s = 0; s < KTOP; ++s) acc += w[s] * vc[id[s]];
    ob[c * PIX + (iy << 6) + x] = acc;
  }
}

extern "C" void kernel_launch(void* const* d_in, const int* in_sizes, int n_in,
                              void* d_out, int out_size, void* d_ws, size_t ws_size,
                              hipStream_t stream) {
  const float* q = (const float*)d_in[0];
  const float* k = (const float*)d_in[1];
  const float* v = (const float*)d_in[2];
  float* out = (float*)d_out;

  float* ws        = (float*)d_ws;
  float* nk        = ws;
  float* kk        = ws + 8192;
  float* cand_cost = ws + 16384;
  int*   cand_idx  = (int*)(ws + 16384 + 262144);

  nk_kernel<<<32, 256, 0, stream>>>(k, nk);
  kk_kernel<<<32, 256, 0, stream>>>(nk, kk);
  cost_topk_kernel<<<512, 256, 0, stream>>>(q, k, kk, cand_cost, cand_idx);
  merge_out_kernel<<<128, 256, 0, stream>>>(cand_cost, cand_idx, v, out);
}

// Round 4
// 153.195 us; speedup vs baseline: 6.8685x; 1.0502x over previous
//
#include <hip/hip_runtime.h>

#define KTOP 8
typedef unsigned short u16;
typedef unsigned int u32;
typedef unsigned long long u64;
typedef short bf16x8 __attribute__((ext_vector_type(8)));   // 8 bf16 = 4 VGPR
typedef float f32x16 __attribute__((ext_vector_type(16)));  // 32x32 acc

// ---------- ws byte layout ----------
// qh  @ 0        : u16[2*64*4096]  1 MB   ([b][y][ pix*64 + (ch ^ ((pix&7)<<3)) ])
// ql  @ 1 MB     : u16[...]        1 MB
// kh  @ 2 MB     : u16[...]        1 MB
// kl  @ 3 MB     : u16[...]        1 MB
// nk  @ 4 MB     : float[8192]
// kk  @ 4 MB+32K : float[8192]
// cand@ 4 MB+64K : u64[2*4096*32]  2 MB
// total ~6.07 MB

__device__ __forceinline__ u16 f2bf(float x) {
  u32 u = __builtin_bit_cast(u32, x);
  u32 r = u + 0x7fffu + ((u >> 16) & 1u);   // RNE
  return (u16)(r >> 16);
}
__device__ __forceinline__ float bf2f(u16 h) {
  u32 u = ((u32)h) << 16;
  return __builtin_bit_cast(float, u);
}
__device__ __forceinline__ u64 packkey(float cost, int jg) {
  u32 u = __builtin_bit_cast(u32, cost);
  u32 ou = ((int)u < 0) ? ~u : (u | 0x80000000u);   // ascending-orderable
  return ((u64)ou << 32) | (u32)jg;                 // tie -> lower idx
}
__device__ __forceinline__ float unpackcost(u64 key) {
  u32 ou = (u32)(key >> 32);
  u32 u = ((int)ou < 0) ? (ou ^ 0x80000000u) : ~ou;
  return __builtin_bit_cast(float, u);
}
// branchless sorted-ascending top-8 insert (min-first); x bubbles the max out
__device__ __forceinline__ void kinsert(u64 (&k8)[KTOP], u64 x) {
#pragma unroll
  for (int p = 0; p < KTOP; ++p) {
    u64 a = k8[p];
    u64 lo = a < x ? a : x;
    u64 hi = a < x ? x : a;
    k8[p] = lo;
    x = hi;
  }
}

// ---------------- kernel 1: transpose + bf16 hi/lo split (+ nk for k) ----------------
// grid 256 = which(2) * b(2) * y(64); block 256
__global__ void prep_kernel(const float* __restrict__ q, const float* __restrict__ k,
                            u16* __restrict__ qh, u16* __restrict__ ql,
                            u16* __restrict__ kh, u16* __restrict__ kl,
                            float* __restrict__ nk) {
  __shared__ float tile[64][65];
  int bid = blockIdx.x;
  int which = bid >> 7;          // 0 = q, 1 = k
  int b = (bid >> 6) & 1;
  int y = bid & 63;
  int t = threadIdx.x;

  const float* src = (which ? k : q) + (size_t)b * (64 * 4096) + (y << 6);
#pragma unroll
  for (int e = 0; e < 16; ++e) {
    int idx = e * 256 + t;
    int c = idx >> 6, x = idx & 63;
    tile[c][x] = src[(c << 12) + x];
  }
  __syncthreads();

  int x = t >> 2, cg = t & 3;
  u16 hi[16], lo[16];
#pragma unroll
  for (int i = 0; i < 16; ++i) {
    float val = tile[cg * 16 + i][x];
    u16 h = f2bf(val);
    hi[i] = h;
    lo[i] = f2bf(val - bf2f(h));
  }
  u16* dh = (which ? kh : qh) + ((size_t)(b * 64 + y) << 12);
  u16* dl = (which ? kl : ql) + ((size_t)(b * 64 + y) << 12);
  int sw = (x & 7) << 3;
#pragma unroll
  for (int cc = 0; cc < 2; ++cc) {
    int base = (x << 6) + ((cg * 16 + cc * 8) ^ sw);
    uint4 wh, wl;
    wh.x = (u32)hi[cc*8+0] | ((u32)hi[cc*8+1] << 16);
    wh.y = (u32)hi[cc*8+2] | ((u32)hi[cc*8+3] << 16);
    wh.z = (u32)hi[cc*8+4] | ((u32)hi[cc*8+5] << 16);
    wh.w = (u32)hi[cc*8+6] | ((u32)hi[cc*8+7] << 16);
    wl.x = (u32)lo[cc*8+0] | ((u32)lo[cc*8+1] << 16);
    wl.y = (u32)lo[cc*8+2] | ((u32)lo[cc*8+3] << 16);
    wl.z = (u32)lo[cc*8+4] | ((u32)lo[cc*8+5] << 16);
    wl.w = (u32)lo[cc*8+6] | ((u32)lo[cc*8+7] << 16);
    *(uint4*)&dh[base] = wh;
    *(uint4*)&dl[base] = wl;
  }
  // nk for k rows (tile unchanged since sync; read-only -> no extra barrier)
  if (which && t < 64) {
    float s = 0.f;
#pragma unroll
    for (int c = 0; c < 64; ++c) { float vv = tile[c][t]; s += vv * vv; }
    nk[(b << 12) + (y << 6) + t] = s;
  }
}

// ---------------- kernel 2: 3x3 zero-padded stencil -> kk ----------------
__global__ void kk_kernel(const float* __restrict__ nk, float* __restrict__ kk) {
  int p = blockIdx.x * blockDim.x + threadIdx.x;
  int b = p >> 12, pix = p & 4095;
  int y = pix >> 6, x = pix & 63;
  float s = 0.f;
#pragma unroll
  for (int di = -1; di <= 1; ++di)
#pragma unroll
    for (int dj = -1; dj <= 1; ++dj) {
      int yy = y + di, xx = x + dj;
      if ((unsigned)yy < 64u && (unsigned)xx < 64u)
        s += nk[(b << 12) + (yy << 6) + xx];
    }
  kk[p] = s;
}

// ---------------- kernel 3: MFMA cost + per-quarter top-8 ----------------
// grid 512 = B*iy*quarter; block 256 (4 waves = 4 32x32 quadrants); 2 blocks/CU.
__launch_bounds__(256, 2)
__global__ void cost_topk_kernel(const u16* __restrict__ qh, const u16* __restrict__ ql,
                                 const u16* __restrict__ kh, const u16* __restrict__ kl,
                                 const float* __restrict__ kkg,
                                 u64* __restrict__ cand) {
  __shared__ __align__(16) u16 ring[3][2][4096];   // [slot][hi/lo][pix*64+swz ch] 48 KB
  __shared__ float Rb[66][67];                     // S tile + zero border      17.3 KB

  int bid = blockIdx.x;
  int b   = bid >> 8;
  int rem = bid & 255;
  int iy  = rem >> 2;
  int qtr = rem & 3;
  int q0  = qtr * 16;

  int tid  = threadIdx.x;
  int lane = tid & 63, wv = tid >> 6;
  int wr = wv >> 1, wc = wv & 1;
  int l31 = lane & 31, lk8 = (lane >> 5) << 3;
  int apix = wr * 32 + l31;
  int bpix = wc * 32 + l31;
  int sx = tid & 63, sseg = tid >> 6, jxs = sseg * 16;

  const u16* qhb = qh + ((size_t)b << 18);
  const u16* qlb = ql + ((size_t)b << 18);
  const u16* khb = kh + ((size_t)b << 18);
  const u16* klb = kl + ((size_t)b << 18);

  const bf16x8 z8 = {0, 0, 0, 0, 0, 0, 0, 0};
  const uint4 z4 = {0u, 0u, 0u, 0u};

  // ---- A fragments: direct global -> VGPR (no LDS) ----
  bf16x8 qa[3][4], qlr[3][4];
  int swA = (apix & 7) << 3;
#pragma unroll
  for (int d = 0; d < 3; ++d) {
    int qy = iy - 1 + d;
    bool ok = (unsigned)qy < 64u;
    int rb = (qy & 63) << 12;
#pragma unroll
    for (int c4 = 0; c4 < 4; ++c4) {
      int idx = (apix << 6) + (((c4 << 4) + lk8) ^ swA);
      bf16x8 th = *(const bf16x8*)&qhb[rb + idx];
      bf16x8 tl = *(const bf16x8*)&qlb[rb + idx];
      qa[d][c4]  = ok ? th : z8;
      qlr[d][c4] = ok ? tl : z8;
    }
  }

  // zero Rb (borders stay zero) + prefill ring rows q0-1..q0+1
  for (int i = tid; i < 66 * 67; i += 256) ((float*)Rb)[i] = 0.f;
  for (int r = q0 - 1; r <= q0 + 1; ++r) {
    int slot = (r + 3) % 3;
    bool ok = (unsigned)r < 64u;
    int rb = (r & 63) << 12;
#pragma unroll
    for (int i = 0; i < 2; ++i) {
      int e = tid * 16 + i * 8;
      uint4 vh = *(const uint4*)&khb[rb + e];
      uint4 vl = *(const uint4*)&klb[rb + e];
      *(uint4*)&ring[slot][0][e] = ok ? vh : z4;
      *(uint4*)&ring[slot][1][e] = ok ? vl : z4;
    }
  }
  __syncthreads();

  u64 k8a[KTOP], k8b[KTOP];
#pragma unroll
  for (int s = 0; s < KTOP; ++s) { k8a[s] = ~0ull; k8b[s] = ~0ull; }

  int swB = (bpix & 7) << 3;

  for (int jt = 0; jt < 16; ++jt) {
    int jy = q0 + jt;

    // prefetch k row jy+2 into registers (pure copy, no cvt)
    int pr = jy + 2;
    bool pwrite = (jt < 15);
    bool pok = pwrite && (pr < 64);
    int prb = (pr & 63) << 12;
    uint4 ph[2], pl[2];
#pragma unroll
    for (int i = 0; i < 2; ++i) {
      int e = tid * 16 + i * 8;
      uint4 vh = *(const uint4*)&khb[prb + e];
      uint4 vl = *(const uint4*)&klb[prb + e];
      ph[i] = pok ? vh : z4;
      pl[i] = pok ? vl : z4;
    }

    // ---- 36 MFMA: S quadrant, K = 3 rows x 4 ch-chunks x {hh, lh, hl} ----
    f32x16 acc;
#pragma unroll
    for (int i = 0; i < 16; ++i) acc[i] = 0.f;
#pragma unroll
    for (int d = 0; d < 3; ++d) {
      int slot = (jy + d + 2) % 3;
      const u16* rh = ring[slot][0];
      const u16* rl = ring[slot][1];
#pragma unroll
      for (int c4 = 0; c4 < 4; ++c4) {
        int idx = (bpix << 6) + (((c4 << 4) + lk8) ^ swB);
        bf16x8 bh = *(const bf16x8*)&rh[idx];
        bf16x8 bl = *(const bf16x8*)&rl[idx];
        acc = __builtin_amdgcn_mfma_f32_32x32x16_bf16(qa[d][c4],  bh, acc, 0, 0, 0);
        acc = __builtin_amdgcn_mfma_f32_32x32x16_bf16(qlr[d][c4], bh, acc, 0, 0, 0);
        acc = __builtin_amdgcn_mfma_f32_32x32x16_bf16(qa[d][c4],  bl, acc, 0, 0, 0);
      }
    }

    __syncthreads();   // all MFMA ds_reads done; slot (jy+2)%3 == (jy-1)%3 free

    // C-write into bordered Rb: col=lane&31, row=(r&3)+8*(r>>2)+4*(lane>>5)
#pragma unroll
    for (int r = 0; r < 16; ++r) {
      int row = wr * 32 + (r & 3) + ((r >> 2) << 3) + ((lane >> 5) << 2);
      Rb[row + 1][wc * 32 + l31 + 1] = acc[r];
    }
    if (pwrite) {
      u16* dh = &ring[pr % 3][0][tid * 16];
      u16* dl = &ring[pr % 3][1][tid * 16];
      *(uint4*)dh = ph[0]; *(uint4*)(dh + 8) = ph[1];
      *(uint4*)dl = pl[0]; *(uint4*)(dl + 8) = pl[1];
    }

    __syncthreads();   // S visible

    // diagonal 3-point stencil + cost + branchless top-8
    float a16[16];
#pragma unroll
    for (int jj = 0; jj < 16; ++jj) a16[jj] = 0.f;
    int xr = sx + 1;
#pragma unroll
    for (int dj = -1; dj <= 1; ++dj) {
      const float* row = &Rb[xr + dj][jxs + dj + 1];
#pragma unroll
      for (int jj = 0; jj < 16; ++jj) a16[jj] += row[jj];
    }
    const float* kkr = kkg + (b << 12) + (jy << 6) + jxs;
    float kv[16];
#pragma unroll
    for (int j4 = 0; j4 < 4; ++j4) *(float4*)&kv[j4 * 4] = *(const float4*)&kkr[j4 * 4];
#pragma unroll
    for (int jj = 0; jj < 16; ++jj) {
      float cost = kv[jj] - 2.f * a16[jj];
      u64 key = packkey(cost, (jy << 6) + jxs + jj);
      if (jj < 8) kinsert(k8a, key); else kinsert(k8b, key);
    }
  }

  // merge the two key sets, then block-level merge of 4 segments -> top-8/qtr
#pragma unroll
  for (int s = 0; s < KTOP; ++s) kinsert(k8a, k8b[s]);

  __syncthreads();
  u64* lbuf = (u64*)ring;   // 64 queries x 32 keys = 16 KB
#pragma unroll
  for (int s = 0; s < KTOP; ++s) lbuf[sx * 32 + sseg * 8 + s] = k8a[s];
  __syncthreads();
  if (tid < 64) {
    u64 m8[KTOP];
#pragma unroll
    for (int s = 0; s < KTOP; ++s) m8[s] = ~0ull;
    for (int t2 = 0; t2 < 32; ++t2) kinsert(m8, lbuf[tid * 32 + t2]);
    u64* dst = cand + ((size_t)((b << 12) + (iy << 6) + tid) << 5) + (qtr << 3);
#pragma unroll
    for (int s = 0; s < KTOP; ++s) dst[s] = m8[s];
  }
}

// ---------------- kernel 4: merge quarters, softmax, gather v ----------------
__global__ void merge_out_kernel(const u64* __restrict__ cand,
                                 const float* __restrict__ v,
                                 float* __restrict__ out) {
  __shared__ float wL[64][9];
  __shared__ int   idL[64][9];
  int bid = blockIdx.x;
  int b = bid >> 6, iy = bid & 63;
  int tid = threadIdx.x;

  if (tid < 64) {
    const u64* src = cand + ((size_t)((b << 12) + (iy << 6) + tid) << 5);
    u64 m8[KTOP];
#pragma unroll
    for (int s = 0; s < KTOP; ++s) m8[s] = ~0ull;
    for (int t2 = 0; t2 < 32; ++t2) kinsert(m8, src[t2]);
    float c8[KTOP];
#pragma unroll
    for (int s = 0; s < KTOP; ++s) c8[s] = unpackcost(m8[s]);
    float m = c8[0];
    float w[KTOP], wsum = 0.f;
#pragma unroll
    for (int s = 0; s < KTOP; ++s) { w[s] = __expf(m - c8[s]); wsum += w[s]; }
    float inv = 1.f / wsum;
#pragma unroll
    for (int s = 0; s < KTOP; ++s) {
      wL[tid][s] = w[s] * inv;
      idL[tid][s] = (int)(m8[s] & 0xffffffffull);
    }
  }
  __syncthreads();

  int x = tid & 63, cq = tid >> 6;
  float w[KTOP]; int id[KTOP];
#pragma unroll
  for (int s = 0; s < KTOP; ++s) { w[s] = wL[x][s]; id[s] = idL[x][s]; }
  const float* vb = v + (size_t)b * (64 * 4096);
  float* ob = out + (size_t)b * (64 * 4096);
#pragma unroll 4
  for (int cc = 0; cc < 16; ++cc) {
    int c = cc * 4 + cq;
    const float* vc = vb + (c << 12);
    float acc = 0.f;
#pragma unroll
    for (int s = 0; s < KTOP; ++s) acc += w[s] * vc[id[s]];
    ob[(c << 12) + (iy << 6) + x] = acc;
  }
}

extern "C" void kernel_launch(void* const* d_in, const int* in_sizes, int n_in,
                              void* d_out, int out_size, void* d_ws, size_t ws_size,
                              hipStream_t stream) {
  const float* q = (const float*)d_in[0];
  const float* k = (const float*)d_in[1];
  const float* v = (const float*)d_in[2];
  float* out = (float*)d_out;

  char* ws = (char*)d_ws;
  u16*   qh   = (u16*)(ws);
  u16*   ql   = (u16*)(ws + (1u << 20));
  u16*   kh   = (u16*)(ws + (2u << 20));
  u16*   kl   = (u16*)(ws + (3u << 20));
  float* nk   = (float*)(ws + (4u << 20));
  float* kkp  = (float*)(ws + (4u << 20) + 32768);
  u64*   cand = (u64*)(ws + (4u << 20) + 65536);

  prep_kernel<<<256, 256, 0, stream>>>(q, k, qh, ql, kh, kl, nk);
  kk_kernel<<<32, 256, 0, stream>>>(nk, kkp);
  cost_topk_kernel<<<512, 256, 0, stream>>>(qh, ql, kh, kl, kkp, cand);
  merge_out_kernel<<<128, 256, 0, stream>>>(cand, v, out);
}

// Round 5
// 94.949 us; speedup vs baseline: 11.0820x; 1.6134x over previous
//
#include <hip/hip_runtime.h>

#define KTOP 8
typedef unsigned short u16;
typedef unsigned int u32;
typedef short bf16x8 __attribute__((ext_vector_type(8)));   // 8 bf16 = 4 VGPR
typedef float f32x16 __attribute__((ext_vector_type(16)));  // 32x32 acc

// ---------- ws byte layout ----------
// qh @0, ql @1M, kh @2M, kl @3M : u16[2*64*4096] each, [b][y][x*64 + (ch^((x&7)<<3))]
// nk @4M (f32 8192), kk @4M+32K (f32 8192)
// cand @4M+64K : u32[2*4096*32]  (1 MB)  quantized keys
// wgt  @5M+64K : f32[2*4096*8]   (256 KB)
// idx  @5M+320K: u32[2*4096*8]   (256 KB)

__device__ __forceinline__ u16 f2bf(float x) {
  u32 u = __builtin_bit_cast(u32, x);
  u32 r = u + 0x7fffu + ((u >> 16) & 1u);
  return (u16)(r >> 16);
}
__device__ __forceinline__ float bf2f(u16 h) {
  u32 u = ((u32)h) << 16;
  return __builtin_bit_cast(float, u);
}
__device__ __forceinline__ u32 ordenc(float c) {
  u32 u = __builtin_bit_cast(u32, c);
  u32 s = (u32)((int)u >> 31);
  return u ^ (s | 0x80000000u);   // monotone float->uint
}
// branchless sorted-ascending top-8, u32 keys: 2 instr per step (min/max)
__device__ __forceinline__ void kins(u32 (&k8)[KTOP], u32 x) {
#pragma unroll
  for (int p = 0; p < KTOP; ++p) {
    u32 a = k8[p];
    u32 mn = a < x ? a : x;
    u32 mx = a < x ? x : a;
    k8[p] = mn;
    x = mx;
  }
}

// ---------------- kernel 1: transpose + bf16 hi/lo split (+ nk for k) ----------------
__global__ void prep_kernel(const float* __restrict__ q, const float* __restrict__ k,
                            u16* __restrict__ qh, u16* __restrict__ ql,
                            u16* __restrict__ kh, u16* __restrict__ kl,
                            float* __restrict__ nk) {
  __shared__ float tile[64][65];
  int bid = blockIdx.x;
  int which = bid >> 7;
  int b = (bid >> 6) & 1;
  int y = bid & 63;
  int t = threadIdx.x;

  const float* src = (which ? k : q) + (size_t)b * (64 * 4096) + (y << 6);
#pragma unroll
  for (int e = 0; e < 16; ++e) {
    int idx = e * 256 + t;
    int c = idx >> 6, x = idx & 63;
    tile[c][x] = src[(c << 12) + x];
  }
  __syncthreads();

  int x = t >> 2, cg = t & 3;
  u16 hi[16], lo[16];
#pragma unroll
  for (int i = 0; i < 16; ++i) {
    float val = tile[cg * 16 + i][x];
    u16 h = f2bf(val);
    hi[i] = h;
    lo[i] = f2bf(val - bf2f(h));
  }
  u16* dh = (which ? kh : qh) + ((size_t)(b * 64 + y) << 12);
  u16* dl = (which ? kl : ql) + ((size_t)(b * 64 + y) << 12);
  int sw = (x & 7) << 3;
#pragma unroll
  for (int cc = 0; cc < 2; ++cc) {
    int base = (x << 6) + ((cg * 16 + cc * 8) ^ sw);
    uint4 wh, wl;
    wh.x = (u32)hi[cc*8+0] | ((u32)hi[cc*8+1] << 16);
    wh.y = (u32)hi[cc*8+2] | ((u32)hi[cc*8+3] << 16);
    wh.z = (u32)hi[cc*8+4] | ((u32)hi[cc*8+5] << 16);
    wh.w = (u32)hi[cc*8+6] | ((u32)hi[cc*8+7] << 16);
    wl.x = (u32)lo[cc*8+0] | ((u32)lo[cc*8+1] << 16);
    wl.y = (u32)lo[cc*8+2] | ((u32)lo[cc*8+3] << 16);
    wl.z = (u32)lo[cc*8+4] | ((u32)lo[cc*8+5] << 16);
    wl.w = (u32)lo[cc*8+6] | ((u32)lo[cc*8+7] << 16);
    *(uint4*)&dh[base] = wh;
    *(uint4*)&dl[base] = wl;
  }
  if (which && t < 64) {
    float s = 0.f;
#pragma unroll
    for (int c = 0; c < 64; ++c) { float vv = tile[c][t]; s += vv * vv; }
    nk[(b << 12) + (y << 6) + t] = s;
  }
}

// ---------------- kernel 2: 3x3 zero-padded stencil -> kk ----------------
__global__ void kk_kernel(const float* __restrict__ nk, float* __restrict__ kk) {
  int p = blockIdx.x * blockDim.x + threadIdx.x;
  int b = p >> 12, pix = p & 4095;
  int y = pix >> 6, x = pix & 63;
  float s = 0.f;
#pragma unroll
  for (int di = -1; di <= 1; ++di)
#pragma unroll
    for (int dj = -1; dj <= 1; ++dj) {
      int yy = y + di, xx = x + dj;
      if ((unsigned)yy < 64u && (unsigned)xx < 64u)
        s += nk[(b << 12) + (yy << 6) + xx];
    }
  kk[p] = s;
}

// ---------------- kernel 3: hi-only MFMA cost + quantized-key top-8 ----------------
// 512 threads = 2 query rows x 4 quadrant-waves; 4-slot shared k-row ring.
// grid 256 = b(2) x rowpair(32) x quarter(4); 2 blocks/CU, 4 waves/SIMD.
__launch_bounds__(512, 4)
__global__ void cost_topk_kernel(const u16* __restrict__ qh,
                                 const u16* __restrict__ kh,
                                 const float* __restrict__ kkg,
                                 u32* __restrict__ cand) {
  __shared__ __align__(16) u16 ring[4][4096];        // 32 KB, slot = row & 3
  __shared__ float RbBuf[2 * 66 * 67 + 4];           // 2 bordered S tiles, 35.4 KB

  int bid = blockIdx.x;
  int b   = bid >> 7;
  int rp  = (bid >> 2) & 31;
  int qtr = bid & 3;
  int q0  = qtr << 4;
  int iy0 = rp << 1;

  int t = threadIdx.x;
  int lane = t & 63;
  int wv = t >> 6;
  int h  = wv >> 2;                 // query-row half (0/1)
  int quad = wv & 3;
  int wr = quad >> 1, wc = quad & 1;
  int l31 = lane & 31, lk8 = (lane >> 5) << 3;
  int apix = (wr << 5) + l31;
  int bpix = (wc << 5) + l31;
  int sx = t & 63, sseg = (t >> 6) & 3, jxs = sseg << 4;
  int iy = iy0 + h;

  const u16* qhb = qh + ((size_t)b << 18);
  const u16* khb = kh + ((size_t)b << 18);

  const bf16x8 z8 = {0,0,0,0,0,0,0,0};
  const uint4 z4 = {0u,0u,0u,0u};

  // A fragments (hi only), rows iy-1..iy+1, direct global->VGPR
  bf16x8 qa[3][4];
  int swA = (apix & 7) << 3;
#pragma unroll
  for (int d = 0; d < 3; ++d) {
    int qy = iy - 1 + d;
    bool ok = (unsigned)qy < 64u;
    int rb = (qy & 63) << 12;
#pragma unroll
    for (int c4 = 0; c4 < 4; ++c4) {
      bf16x8 v = *(const bf16x8*)&qhb[rb + (apix << 6) + (((c4 << 4) + lk8) ^ swA)];
      qa[d][c4] = ok ? v : z8;
    }
  }

  // zero Rb (borders stay zero); prefill ring rows q0-1..q0+1
  for (int i = t; i < 2 * 66 * 67 + 4; i += 512) RbBuf[i] = 0.f;
#pragma unroll
  for (int d = 0; d < 3; ++d) {
    int r = q0 - 1 + d;
    bool ok = (unsigned)r < 64u;
    uint4 v = ok ? *(const uint4*)&khb[((r & 63) << 12) + (t << 3)] : z4;
    *(uint4*)&ring[(r + 4) & 3][t << 3] = v;
  }
  __syncthreads();

  u32 k8a[KTOP], k8b[KTOP];
#pragma unroll
  for (int s = 0; s < KTOP; ++s) { k8a[s] = 0xFFFFFFFFu; k8b[s] = 0xFFFFFFFFu; }

  int swB = (bpix & 7) << 3;
  float* Rh = &RbBuf[h * (66 * 67)];

  for (int jt = 0; jt < 16; ++jt) {
    int jy = q0 + jt;
    // prefetch next ring row (global->reg; LDS write after barrier)
    int pr = jy + 2;
    bool pok = (jt < 15) && (pr < 64);
    uint4 pf = pok ? *(const uint4*)&khb[((pr & 63) << 12) + (t << 3)] : z4;

    f32x16 acc;
#pragma unroll
    for (int i = 0; i < 16; ++i) acc[i] = 0.f;
#pragma unroll
    for (int d = 0; d < 3; ++d) {
      const u16* rg = ring[(jy - 1 + d) & 3];
#pragma unroll
      for (int c4 = 0; c4 < 4; ++c4) {
        bf16x8 bh = *(const bf16x8*)&rg[(bpix << 6) + (((c4 << 4) + lk8) ^ swB)];
        acc = __builtin_amdgcn_mfma_f32_32x32x16_bf16(qa[d][c4], bh, acc, 0, 0, 0);
      }
    }
    __syncthreads();   // prev stencil reads of Rb + this jt's ring reads done

    // C-write (col=lane&31, row=(r&3)+8*(r>>2)+4*(lane>>5)) into bordered tile
#pragma unroll
    for (int r = 0; r < 16; ++r) {
      int row = (wr << 5) + (r & 3) + ((r >> 2) << 3) + ((lane >> 5) << 2);
      Rh[(row + 1) * 67 + (wc << 5) + l31 + 1] = acc[r];
    }
    if (jt < 15) *(uint4*)&ring[pr & 3][t << 3] = pf;
    __syncthreads();   // S + ring row visible

    // diagonal 3-point stencil + cost + branchless top-8 (two chains for ILP)
    float a16[16];
    {
      const float* rm = &Rh[sx * 67 + jxs];            // row sx   (= xr-1)
      const float* rc = &Rh[(sx + 1) * 67 + jxs];      // row xr
      const float* rq = &Rh[(sx + 2) * 67 + jxs];      // row xr+1
#pragma unroll
      for (int jj = 0; jj < 16; ++jj)
        a16[jj] = rm[jj] + rc[jj + 1] + rq[jj + 2];
    }
    const float* kkr = kkg + (b << 12) + (jy << 6) + jxs;
    int jbase = (jy << 6) + jxs;
#pragma unroll
    for (int jj = 0; jj < 16; ++jj) {
      float cost = kkr[jj] - 2.f * a16[jj];
      u32 key = (ordenc(cost) & 0xFFFFF000u) | (u32)(jbase + jj);
      if (jj & 1) kins(k8b, key); else kins(k8a, key);
    }
  }

#pragma unroll
  for (int s = 0; s < KTOP; ++s) kins(k8a, k8b[s]);

  // block merge: 4 segments per query -> per-quarter top-8
  __syncthreads();
  u32* lbuf = (u32*)ring;   // 128 queries x 32 keys = 16 KB
  int qloc = (h << 6) + sx;
#pragma unroll
  for (int s = 0; s < KTOP; ++s) lbuf[(qloc << 5) + (sseg << 3) + s] = k8a[s];
  __syncthreads();
  if (t < 128) {
    u32 m8[KTOP];
#pragma unroll
    for (int s = 0; s < KTOP; ++s) m8[s] = 0xFFFFFFFFu;
    for (int e = 0; e < 32; ++e) kins(m8, lbuf[(t << 5) + e]);
    int qi = ((iy0 + (t >> 6)) << 6) + (t & 63);
    u32* dst = cand + (((size_t)(b << 12) + qi) << 5) + (qtr << 3);
#pragma unroll
    for (int s = 0; s < KTOP; ++s) dst[s] = m8[s];
  }
}

// ---------------- kernel 4: merge 32 keys, EXACT fp32 rescore, softmax ----------------
// grid 512, block 128: one (query, slot) pair per thread.
__global__ void rescore_kernel(const u16* __restrict__ qh, const u16* __restrict__ ql,
                               const u16* __restrict__ kh, const u16* __restrict__ kl,
                               const float* __restrict__ kkg, const u32* __restrict__ cand,
                               float* __restrict__ wgt, u32* __restrict__ idxo) {
  int gid = blockIdx.x * 128 + threadIdx.x;   // 0..65535
  int b = gid >> 15;
  int qi = (gid >> 3) & 4095;
  int s = gid & 7;

  const u32* src = cand + (((size_t)(b << 12) + qi) << 5);
  u32 m8[KTOP];
#pragma unroll
  for (int e = 0; e < KTOP; ++e) m8[e] = 0xFFFFFFFFu;
  for (int e = 0; e < 32; ++e) kins(m8, src[e]);
  int j = m8[s] & 0xFFF;

  int yi = qi >> 6, xi = qi & 63;
  int yj = j >> 6, xj = j & 63;
  const u16* qhb = qh + ((size_t)b << 18);
  const u16* qlb = ql + ((size_t)b << 18);
  const u16* khb = kh + ((size_t)b << 18);
  const u16* klb = kl + ((size_t)b << 18);

  float acc = 0.f;
  for (int di = 0; di < 3; ++di) {
    int qy = yi + di - 1, ky = yj + di - 1;
    if ((unsigned)qy >= 64u || (unsigned)ky >= 64u) continue;
    const u16* qhr = qhb + ((size_t)qy << 12);
    const u16* qlr = qlb + ((size_t)qy << 12);
    const u16* khr = khb + ((size_t)ky << 12);
    const u16* klr = klb + ((size_t)ky << 12);
    for (int dj = 0; dj < 3; ++dj) {
      int qx = xi + dj - 1, kx = xj + dj - 1;
      if ((unsigned)qx >= 64u || (unsigned)kx >= 64u) continue;
      int qb2 = (qx << 6), qsw = (qx & 7) << 3;
      int kb2 = (kx << 6), ksw = (kx & 7) << 3;
#pragma unroll
      for (int c8 = 0; c8 < 8; ++c8) {
        uint4 qhv = *(const uint4*)&qhr[qb2 + ((c8 * 8) ^ qsw)];
        uint4 qlv = *(const uint4*)&qlr[qb2 + ((c8 * 8) ^ qsw)];
        uint4 khv = *(const uint4*)&khr[kb2 + ((c8 * 8) ^ ksw)];
        uint4 klv = *(const uint4*)&klr[kb2 + ((c8 * 8) ^ ksw)];
        const u32* qhw = (const u32*)&qhv;
        const u32* qlw = (const u32*)&qlv;
        const u32* khw = (const u32*)&khv;
        const u32* klw = (const u32*)&klv;
#pragma unroll
        for (int e = 0; e < 4; ++e) {
          float ql0 = __builtin_bit_cast(float, qhw[e] << 16) +
                      __builtin_bit_cast(float, qlw[e] << 16);
          float qh1 = __builtin_bit_cast(float, qhw[e] & 0xFFFF0000u) +
                      __builtin_bit_cast(float, qlw[e] & 0xFFFF0000u);
          float kl0 = __builtin_bit_cast(float, khw[e] << 16) +
                      __builtin_bit_cast(float, klw[e] << 16);
          float kh1 = __builtin_bit_cast(float, khw[e] & 0xFFFF0000u) +
                      __builtin_bit_cast(float, klw[e] & 0xFFFF0000u);
          acc = fmaf(ql0, kl0, acc);
          acc = fmaf(qh1, kh1, acc);
        }
      }
    }
  }
  float cost = kkg[(b << 12) + j] - 2.f * acc;

  // softmax across the 8 slots of this query (aligned 8-lane groups)
  float m = cost;
#pragma unroll
  for (int off = 1; off < 8; off <<= 1) m = fminf(m, __shfl_xor(m, off));
  float w = __expf(m - cost);
  float ws = w;
#pragma unroll
  for (int off = 1; off < 8; off <<= 1) ws += __shfl_xor(ws, off);
  size_t o = (((size_t)(b << 12) + qi) << 3) + s;
  wgt[o] = w / ws;
  idxo[o] = (u32)j;
}

// ---------------- kernel 5: gather v, write output ----------------
// grid 256 = b(2) x iy(64) x chalf(2); block 256.
__global__ void out_kernel(const float* __restrict__ wgt, const u32* __restrict__ idxo,
                           const float* __restrict__ v, float* __restrict__ out) {
  int bid = blockIdx.x;
  int b = bid >> 7, iy = (bid >> 1) & 63, chalf = bid & 1;
  int t = threadIdx.x;
  int x = t & 63, cq = t >> 6;
  int qi = (iy << 6) + x;
  const float* wp = wgt + (((size_t)(b << 12) + qi) << 3);
  const u32* ip = idxo + (((size_t)(b << 12) + qi) << 3);
  float w[8]; u32 id[8];
#pragma unroll
  for (int s = 0; s < 8; ++s) { w[s] = wp[s]; id[s] = ip[s]; }
  const float* vb = v + ((size_t)b << 18);
  float* ob = out + ((size_t)b << 18);
#pragma unroll
  for (int cc = 0; cc < 8; ++cc) {
    int c = (chalf << 5) + (cc << 2) + cq;
    const float* vc = vb + (c << 12);
    float acc = 0.f;
#pragma unroll
    for (int s = 0; s < 8; ++s) acc += w[s] * vc[id[s]];
    ob[(c << 12) + qi] = acc;
  }
}

extern "C" void kernel_launch(void* const* d_in, const int* in_sizes, int n_in,
                              void* d_out, int out_size, void* d_ws, size_t ws_size,
                              hipStream_t stream) {
  const float* q = (const float*)d_in[0];
  const float* k = (const float*)d_in[1];
  const float* v = (const float*)d_in[2];
  float* out = (float*)d_out;

  char* ws = (char*)d_ws;
  u16*   qh   = (u16*)(ws);
  u16*   ql   = (u16*)(ws + (1u << 20));
  u16*   kh   = (u16*)(ws + (2u << 20));
  u16*   kl   = (u16*)(ws + (3u << 20));
  float* nk   = (float*)(ws + (4u << 20));
  float* kkp  = (float*)(ws + (4u << 20) + 32768);
  u32*   cand = (u32*)(ws + (4u << 20) + 65536);
  float* wgt  = (float*)(ws + (5u << 20) + 65536);
  u32*   idxo = (u32*)(ws + (5u << 20) + 65536 + 262144);

  prep_kernel<<<256, 256, 0, stream>>>(q, k, qh, ql, kh, kl, nk);
  kk_kernel<<<32, 256, 0, stream>>>(nk, kkp);
  cost_topk_kernel<<<256, 512, 0, stream>>>(qh, kh, kkp, cand);
  rescore_kernel<<<512, 128, 0, stream>>>(qh, ql, kh, kl, kkp, cand, wgt, idxo);
  out_kernel<<<256, 256, 0, stream>>>(wgt, idxo, v, out);
}

// Round 6
// 90.369 us; speedup vs baseline: 11.6437x; 1.0507x over previous
//
#include <hip/hip_runtime.h>

#define KTOP 8
typedef unsigned short u16;
typedef unsigned int u32;
typedef short bf16x8 __attribute__((ext_vector_type(8)));   // 8 bf16 = 4 VGPR
typedef float f32x16 __attribute__((ext_vector_type(16)));  // 32x32 acc

// ---------- ws byte layout ----------
// qh @0, ql @1M, kh @2M, kl @3M : u16[2*64*4096] each, [b][y][x*64 + (ch^((x&7)<<3))]
// nk @4M (f32 8192), kk @4M+32K (f32 8192)
// cand @4M+64K : u32[2*4096*64]  (2 MB)  quantized keys
// wgt  @6M+64K : f32[2*4096*8]   (256 KB)
// idx  @6M+320K: u32[2*4096*8]   (256 KB)

__device__ __forceinline__ u16 f2bf(float x) {
  u32 u = __builtin_bit_cast(u32, x);
  u32 r = u + 0x7fffu + ((u >> 16) & 1u);
  return (u16)(r >> 16);
}
__device__ __forceinline__ float bf2f(u16 h) {
  u32 u = ((u32)h) << 16;
  return __builtin_bit_cast(float, u);
}
__device__ __forceinline__ u32 ordenc(float c) {
  u32 u = __builtin_bit_cast(u32, c);
  u32 s = (u32)((int)u >> 31);
  return u ^ (s | 0x80000000u);   // monotone float->uint
}
// branchless sorted-ascending top-8, u32 keys: 2 instr per step (min/max)
__device__ __forceinline__ void kins(u32 (&k8)[KTOP], u32 x) {
#pragma unroll
  for (int p = 0; p < KTOP; ++p) {
    u32 a = k8[p];
    u32 mn = a < x ? a : x;
    u32 mx = a < x ? x : a;
    k8[p] = mn;
    x = mx;
  }
}

// ---------------- kernel 1: transpose + bf16 hi/lo split (+ nk for k) ----------------
__global__ void prep_kernel(const float* __restrict__ q, const float* __restrict__ k,
                            u16* __restrict__ qh, u16* __restrict__ ql,
                            u16* __restrict__ kh, u16* __restrict__ kl,
                            float* __restrict__ nk) {
  __shared__ float tile[64][65];
  int bid = blockIdx.x;
  int which = bid >> 7;
  int b = (bid >> 6) & 1;
  int y = bid & 63;
  int t = threadIdx.x;

  const float* src = (which ? k : q) + (size_t)b * (64 * 4096) + (y << 6);
#pragma unroll
  for (int e = 0; e < 16; ++e) {
    int idx = e * 256 + t;
    int c = idx >> 6, x = idx & 63;
    tile[c][x] = src[(c << 12) + x];
  }
  __syncthreads();

  int x = t >> 2, cg = t & 3;
  u16 hi[16], lo[16];
#pragma unroll
  for (int i = 0; i < 16; ++i) {
    float val = tile[cg * 16 + i][x];
    u16 h = f2bf(val);
    hi[i] = h;
    lo[i] = f2bf(val - bf2f(h));
  }
  u16* dh = (which ? kh : qh) + ((size_t)(b * 64 + y) << 12);
  u16* dl = (which ? kl : ql) + ((size_t)(b * 64 + y) << 12);
  int sw = (x & 7) << 3;
#pragma unroll
  for (int cc = 0; cc < 2; ++cc) {
    int base = (x << 6) + ((cg * 16 + cc * 8) ^ sw);
    uint4 wh, wl;
    wh.x = (u32)hi[cc*8+0] | ((u32)hi[cc*8+1] << 16);
    wh.y = (u32)hi[cc*8+2] | ((u32)hi[cc*8+3] << 16);
    wh.z = (u32)hi[cc*8+4] | ((u32)hi[cc*8+5] << 16);
    wh.w = (u32)hi[cc*8+6] | ((u32)hi[cc*8+7] << 16);
    wl.x = (u32)lo[cc*8+0] | ((u32)lo[cc*8+1] << 16);
    wl.y = (u32)lo[cc*8+2] | ((u32)lo[cc*8+3] << 16);
    wl.z = (u32)lo[cc*8+4] | ((u32)lo[cc*8+5] << 16);
    wl.w = (u32)lo[cc*8+6] | ((u32)lo[cc*8+7] << 16);
    *(uint4*)&dh[base] = wh;
    *(uint4*)&dl[base] = wl;
  }
  if (which && t < 64) {
    float s = 0.f;
#pragma unroll
    for (int c = 0; c < 64; ++c) { float vv = tile[c][t]; s += vv * vv; }
    nk[(b << 12) + (y << 6) + t] = s;
  }
}

// ---------------- kernel 2: 3x3 zero-padded stencil -> kk ----------------
__global__ void kk_kernel(const float* __restrict__ nk, float* __restrict__ kk) {
  int p = blockIdx.x * blockDim.x + threadIdx.x;
  int b = p >> 12, pix = p & 4095;
  int y = pix >> 6, x = pix & 63;
  float s = 0.f;
#pragma unroll
  for (int di = -1; di <= 1; ++di)
#pragma unroll
    for (int dj = -1; dj <= 1; ++dj) {
      int yy = y + di, xx = x + dj;
      if ((unsigned)yy < 64u && (unsigned)xx < 64u)
        s += nk[(b << 12) + (yy << 6) + xx];
    }
  kk[p] = s;
}

// ---------------- kernel 3: hi-only MFMA cost + quantized-key top-8 ----------------
// 512 threads = 2 query rows x 4 quadrant-waves; keys = 8 rows (one eighth).
// grid 512 = b(2) x rowpair(32) x eighth(8); 2 blocks/CU, 16 waves/CU.
__launch_bounds__(512, 4)
__global__ void cost_topk_kernel(const u16* __restrict__ qh,
                                 const u16* __restrict__ kh,
                                 const float* __restrict__ kkg,
                                 u32* __restrict__ cand) {
  __shared__ __align__(16) u16 ring[4][4096];        // 32 KB, slot = row & 3
  __shared__ float RbBuf[2 * 66 * 67 + 4];           // 2 bordered S tiles, 35.4 KB

  int bid = blockIdx.x;
  int b   = bid >> 8;
  int rp  = (bid >> 3) & 31;
  int e8  = bid & 7;
  int q0  = e8 << 3;
  int iy0 = rp << 1;

  int t = threadIdx.x;
  int lane = t & 63;
  int wv = t >> 6;
  int h  = wv >> 2;                 // query-row half (0/1)
  int quad = wv & 3;
  int wr = quad >> 1, wc = quad & 1;
  int l31 = lane & 31, lk8 = (lane >> 5) << 3;
  int apix = (wr << 5) + l31;
  int bpix = (wc << 5) + l31;
  int sx = t & 63, sseg = (t >> 6) & 3, jxs = sseg << 4;
  int iy = iy0 + h;

  const u16* qhb = qh + ((size_t)b << 18);
  const u16* khb = kh + ((size_t)b << 18);

  const bf16x8 z8 = {0,0,0,0,0,0,0,0};
  const uint4 z4 = {0u,0u,0u,0u};

  // A fragments (hi only), rows iy-1..iy+1, direct global->VGPR
  bf16x8 qa[3][4];
  int swA = (apix & 7) << 3;
#pragma unroll
  for (int d = 0; d < 3; ++d) {
    int qy = iy - 1 + d;
    bool ok = (unsigned)qy < 64u;
    int rb = (qy & 63) << 12;
#pragma unroll
    for (int c4 = 0; c4 < 4; ++c4) {
      bf16x8 v = *(const bf16x8*)&qhb[rb + (apix << 6) + (((c4 << 4) + lk8) ^ swA)];
      qa[d][c4] = ok ? v : z8;
    }
  }

  // zero Rb (borders stay zero); prefill ring rows q0-1..q0+1
  for (int i = t; i < 2 * 66 * 67 + 4; i += 512) RbBuf[i] = 0.f;
#pragma unroll
  for (int d = 0; d < 3; ++d) {
    int r = q0 - 1 + d;
    bool ok = (unsigned)r < 64u;
    uint4 v = ok ? *(const uint4*)&khb[((r & 63) << 12) + (t << 3)] : z4;
    *(uint4*)&ring[(r + 4) & 3][t << 3] = v;
  }
  __syncthreads();

  u32 k8a[KTOP], k8b[KTOP];
#pragma unroll
  for (int s = 0; s < KTOP; ++s) { k8a[s] = 0xFFFFFFFFu; k8b[s] = 0xFFFFFFFFu; }

  int swB = (bpix & 7) << 3;
  float* Rh = &RbBuf[h * (66 * 67)];

  for (int jt = 0; jt < 8; ++jt) {
    int jy = q0 + jt;
    // prefetch next ring row (global->reg; LDS write after barrier)
    int pr = jy + 2;
    bool pok = (jt < 7) && (pr < 64);
    uint4 pf = pok ? *(const uint4*)&khb[((pr & 63) << 12) + (t << 3)] : z4;

    f32x16 acc;
#pragma unroll
    for (int i = 0; i < 16; ++i) acc[i] = 0.f;
#pragma unroll
    for (int d = 0; d < 3; ++d) {
      const u16* rg = ring[(jy - 1 + d) & 3];
#pragma unroll
      for (int c4 = 0; c4 < 4; ++c4) {
        bf16x8 bh = *(const bf16x8*)&rg[(bpix << 6) + (((c4 << 4) + lk8) ^ swB)];
        acc = __builtin_amdgcn_mfma_f32_32x32x16_bf16(qa[d][c4], bh, acc, 0, 0, 0);
      }
    }
    __syncthreads();   // prev stencil reads of Rb done (ring write slot is disjoint)

    // C-write (col=lane&31, row=(r&3)+8*(r>>2)+4*(lane>>5)) into bordered tile
#pragma unroll
    for (int r = 0; r < 16; ++r) {
      int row = (wr << 5) + (r & 3) + ((r >> 2) << 3) + ((lane >> 5) << 2);
      Rh[(row + 1) * 67 + (wc << 5) + l31 + 1] = acc[r];
    }
    if (jt < 7) *(uint4*)&ring[pr & 3][t << 3] = pf;
    __syncthreads();   // S + ring row visible

    // diagonal 3-point stencil + cost + branchless top-8 (two chains for ILP)
    float a16[16];
    {
      const float* rm = &Rh[sx * 67 + jxs];            // row sx-1 (border-shifted)
      const float* rc = &Rh[(sx + 1) * 67 + jxs];      // row sx
      const float* rq = &Rh[(sx + 2) * 67 + jxs];      // row sx+1
#pragma unroll
      for (int jj = 0; jj < 16; ++jj)
        a16[jj] = rm[jj] + rc[jj + 1] + rq[jj + 2];
    }
    const float* kkr = kkg + (b << 12) + (jy << 6) + jxs;
    int jbase = (jy << 6) + jxs;
#pragma unroll
    for (int jj = 0; jj < 16; ++jj) {
      float cost = kkr[jj] - 2.f * a16[jj];
      u32 key = (ordenc(cost) & 0xFFFFF000u) | (u32)(jbase + jj);
      if (jj & 1) kins(k8b, key); else kins(k8a, key);
    }
  }

#pragma unroll
  for (int s = 0; s < KTOP; ++s) kins(k8a, k8b[s]);

  // block merge: 4 segments per query -> per-eighth top-8
  __syncthreads();
  u32* lbuf = (u32*)ring;   // 128 queries x 32 keys = 16 KB
  int qloc = (h << 6) + sx;
#pragma unroll
  for (int s = 0; s < KTOP; ++s) lbuf[(qloc << 5) + (sseg << 3) + s] = k8a[s];
  __syncthreads();
  if (t < 128) {
    u32 m8[KTOP];
#pragma unroll
    for (int s = 0; s < KTOP; ++s) m8[s] = 0xFFFFFFFFu;
    for (int e = 0; e < 32; ++e) kins(m8, lbuf[(t << 5) + e]);
    int qi = ((iy0 + (t >> 6)) << 6) + (t & 63);
    u32* dst = cand + (((size_t)(b << 12) + qi) << 6) + (e8 << 3);
#pragma unroll
    for (int s = 0; s < KTOP; ++s) dst[s] = m8[s];
  }
}

// ---------------- kernel 4: merge 64 keys, EXACT fp32 rescore, softmax ----------------
// grid 512, block 128: one (query, slot) pair per thread.
__global__ void rescore_kernel(const u16* __restrict__ qh, const u16* __restrict__ ql,
                               const u16* __restrict__ kh, const u16* __restrict__ kl,
                               const float* __restrict__ kkg, const u32* __restrict__ cand,
                               float* __restrict__ wgt, u32* __restrict__ idxo) {
  int gid = blockIdx.x * 128 + threadIdx.x;   // 0..65535
  int b = gid >> 15;
  int qi = (gid >> 3) & 4095;
  int s = gid & 7;

  const u32* src = cand + (((size_t)(b << 12) + qi) << 6);
  u32 m8[KTOP];
#pragma unroll
  for (int e = 0; e < KTOP; ++e) m8[e] = 0xFFFFFFFFu;
  for (int e = 0; e < 64; ++e) kins(m8, src[e]);
  int j = m8[s] & 0xFFF;

  int yi = qi >> 6, xi = qi & 63;
  int yj = j >> 6, xj = j & 63;
  const u16* qhb = qh + ((size_t)b << 18);
  const u16* qlb = ql + ((size_t)b << 18);
  const u16* khb = kh + ((size_t)b << 18);
  const u16* klb = kl + ((size_t)b << 18);

  float acc = 0.f;
  for (int di = 0; di < 3; ++di) {
    int qy = yi + di - 1, ky = yj + di - 1;
    if ((unsigned)qy >= 64u || (unsigned)ky >= 64u) continue;
    const u16* qhr = qhb + ((size_t)qy << 12);
    const u16* qlr = qlb + ((size_t)qy << 12);
    const u16* khr = khb + ((size_t)ky << 12);
    const u16* klr = klb + ((size_t)ky << 12);
    for (int dj = 0; dj < 3; ++dj) {
      int qx = xi + dj - 1, kx = xj + dj - 1;
      if ((unsigned)qx >= 64u || (unsigned)kx >= 64u) continue;
      int qb2 = (qx << 6), qsw = (qx & 7) << 3;
      int kb2 = (kx << 6), ksw = (kx & 7) << 3;
#pragma unroll
      for (int c8 = 0; c8 < 8; ++c8) {
        uint4 qhv = *(const uint4*)&qhr[qb2 + ((c8 * 8) ^ qsw)];
        uint4 qlv = *(const uint4*)&qlr[qb2 + ((c8 * 8) ^ qsw)];
        uint4 khv = *(const uint4*)&khr[kb2 + ((c8 * 8) ^ ksw)];
        uint4 klv = *(const uint4*)&klr[kb2 + ((c8 * 8) ^ ksw)];
        const u32* qhw = (const u32*)&qhv;
        const u32* qlw = (const u32*)&qlv;
        const u32* khw = (const u32*)&khv;
        const u32* klw = (const u32*)&klv;
#pragma unroll
        for (int e = 0; e < 4; ++e) {
          float ql0 = __builtin_bit_cast(float, qhw[e] << 16) +
                      __builtin_bit_cast(float, qlw[e] << 16);
          float qh1 = __builtin_bit_cast(float, qhw[e] & 0xFFFF0000u) +
                      __builtin_bit_cast(float, qlw[e] & 0xFFFF0000u);
          float kl0 = __builtin_bit_cast(float, khw[e] << 16) +
                      __builtin_bit_cast(float, klw[e] << 16);
          float kh1 = __builtin_bit_cast(float, khw[e] & 0xFFFF0000u) +
                      __builtin_bit_cast(float, klw[e] & 0xFFFF0000u);
          acc = fmaf(ql0, kl0, acc);
          acc = fmaf(qh1, kh1, acc);
        }
      }
    }
  }
  float cost = kkg[(b << 12) + j] - 2.f * acc;

  // softmax across the 8 slots of this query (aligned 8-lane groups)
  float m = cost;
#pragma unroll
  for (int off = 1; off < 8; off <<= 1) m = fminf(m, __shfl_xor(m, off));
  float w = __expf(m - cost);
  float ws = w;
#pragma unroll
  for (int off = 1; off < 8; off <<= 1) ws += __shfl_xor(ws, off);
  size_t o = (((size_t)(b << 12) + qi) << 3) + s;
  wgt[o] = w / ws;
  idxo[o] = (u32)j;
}

// ---------------- kernel 5: gather v, write output ----------------
// grid 256 = b(2) x iy(64) x chalf(2); block 256.
__global__ void out_kernel(const float* __restrict__ wgt, const u32* __restrict__ idxo,
                           const float* __restrict__ v, float* __restrict__ out) {
  int bid = blockIdx.x;
  int b = bid >> 7, iy = (bid >> 1) & 63, chalf = bid & 1;
  int t = threadIdx.x;
  int x = t & 63, cq = t >> 6;
  int qi = (iy << 6) + x;
  const float* wp = wgt + (((size_t)(b << 12) + qi) << 3);
  const u32* ip = idxo + (((size_t)(b << 12) + qi) << 3);
  float w[8]; u32 id[8];
#pragma unroll
  for (int s = 0; s < 8; ++s) { w[s] = wp[s]; id[s] = ip[s]; }
  const float* vb = v + ((size_t)b << 18);
  float* ob = out + ((size_t)b << 18);
#pragma unroll
  for (int cc = 0; cc < 8; ++cc) {
    int c = (chalf << 5) + (cc << 2) + cq;
    const float* vc = vb + (c << 12);
    float acc = 0.f;
#pragma unroll
    for (int s = 0; s < 8; ++s) acc += w[s] * vc[id[s]];
    ob[(c << 12) + qi] = acc;
  }
}

extern "C" void kernel_launch(void* const* d_in, const int* in_sizes, int n_in,
                              void* d_out, int out_size, void* d_ws, size_t ws_size,
                              hipStream_t stream) {
  const float* q = (const float*)d_in[0];
  const float* k = (const float*)d_in[1];
  const float* v = (const float*)d_in[2];
  float* out = (float*)d_out;

  char* ws = (char*)d_ws;
  u16*   qh   = (u16*)(ws);
  u16*   ql   = (u16*)(ws + (1u << 20));
  u16*   kh   = (u16*)(ws + (2u << 20));
  u16*   kl   = (u16*)(ws + (3u << 20));
  float* nk   = (float*)(ws + (4u << 20));
  float* kkp  = (float*)(ws + (4u << 20) + 32768);
  u32*   cand = (u32*)(ws + (4u << 20) + 65536);
  float* wgt  = (float*)(ws + (6u << 20) + 65536);
  u32*   idxo = (u32*)(ws + (6u << 20) + 65536 + 262144);

  prep_kernel<<<256, 256, 0, stream>>>(q, k, qh, ql, kh, kl, nk);
  kk_kernel<<<32, 256, 0, stream>>>(nk, kkp);
  cost_topk_kernel<<<512, 512, 0, stream>>>(qh, kh, kkp, cand);
  rescore_kernel<<<512, 128, 0, stream>>>(qh, ql, kh, kl, kkp, cand, wgt, idxo);
  out_kernel<<<256, 256, 0, stream>>>(wgt, idxo, v, out);
}

// Round 7
// 79.312 us; speedup vs baseline: 13.2668x; 1.1394x over previous
//
#include <hip/hip_runtime.h>

#define KTOP 8
typedef unsigned short u16;
typedef unsigned int u32;
typedef short bf16x8 __attribute__((ext_vector_type(8)));   // 8 bf16 = 4 VGPR
typedef float f32x16 __attribute__((ext_vector_type(16)));  // 32x32 acc

// ---------- ws byte layout ----------
// qh @0, ql @1M, kh @2M, kl @3M : u16[2*64*4096] each, [b][y][x*64 + (ch^((x&7)<<3))]
// nk @4M (f32 8192), kk @4M+32K (f32 8192)
// cand @4M+64K : u32[2*4096*64]  (2 MB)  quantized keys
// vT   @6M+64K : f32[2*4096*64]  (2 MB)  v transposed [b][pix][ch]  (optional)

__device__ __forceinline__ u16 f2bf(float x) {
  u32 u = __builtin_bit_cast(u32, x);
  u32 r = u + 0x7fffu + ((u >> 16) & 1u);
  return (u16)(r >> 16);
}
__device__ __forceinline__ float bf2f(u16 h) {
  u32 u = ((u32)h) << 16;
  return __builtin_bit_cast(float, u);
}
__device__ __forceinline__ u32 ordenc(float c) {
  u32 u = __builtin_bit_cast(u32, c);
  u32 s = (u32)((int)u >> 31);
  return u ^ (s | 0x80000000u);   // monotone float->uint
}
__device__ __forceinline__ void kins(u32 (&k8)[KTOP], u32 x) {
#pragma unroll
  for (int p = 0; p < KTOP; ++p) {
    u32 a = k8[p];
    u32 mn = a < x ? a : x;
    u32 mx = a < x ? x : a;
    k8[p] = mn;
    x = mx;
  }
}

// ---------------- kernel 1: transpose + bf16 hi/lo split (+ nk) + vT ----------------
// grid 256 (+128 if vt): bid<256: which=q/k; else v-transpose.
__global__ void prep_kernel(const float* __restrict__ q, const float* __restrict__ k,
                            const float* __restrict__ v,
                            u16* __restrict__ qh, u16* __restrict__ ql,
                            u16* __restrict__ kh, u16* __restrict__ kl,
                            float* __restrict__ vt, float* __restrict__ nk) {
  __shared__ float tile[64][65];
  int bid = blockIdx.x;
  int t = threadIdx.x;

  if (bid >= 256) {                       // ---- v transpose path ----
    int r = bid - 256;
    int b = r >> 6, y = r & 63;
    const float* src = v + (size_t)b * (64 * 4096) + (y << 6);
#pragma unroll
    for (int e = 0; e < 16; ++e) {
      int idx = e * 256 + t;
      int c = idx >> 6, x = idx & 63;
      tile[c][x] = src[(c << 12) + x];
    }
    __syncthreads();
    int x = t >> 2, cg = t & 3;
    float* dst = vt + ((size_t)b << 18) + (((y << 6) + x) << 6) + (cg << 4);
#pragma unroll
    for (int i4 = 0; i4 < 4; ++i4) {
      float4 w;
      w.x = tile[cg * 16 + i4 * 4 + 0][x];
      w.y = tile[cg * 16 + i4 * 4 + 1][x];
      w.z = tile[cg * 16 + i4 * 4 + 2][x];
      w.w = tile[cg * 16 + i4 * 4 + 3][x];
      *(float4*)&dst[i4 * 4] = w;
    }
    return;
  }

  int which = bid >> 7;
  int b = (bid >> 6) & 1;
  int y = bid & 63;
  const float* src = (which ? k : q) + (size_t)b * (64 * 4096) + (y << 6);
#pragma unroll
  for (int e = 0; e < 16; ++e) {
    int idx = e * 256 + t;
    int c = idx >> 6, x = idx & 63;
    tile[c][x] = src[(c << 12) + x];
  }
  __syncthreads();

  int x = t >> 2, cg = t & 3;
  u16 hi[16], lo[16];
#pragma unroll
  for (int i = 0; i < 16; ++i) {
    float val = tile[cg * 16 + i][x];
    u16 h = f2bf(val);
    hi[i] = h;
    lo[i] = f2bf(val - bf2f(h));
  }
  u16* dh = (which ? kh : qh) + ((size_t)(b * 64 + y) << 12);
  u16* dl = (which ? kl : ql) + ((size_t)(b * 64 + y) << 12);
  int sw = (x & 7) << 3;
#pragma unroll
  for (int cc = 0; cc < 2; ++cc) {
    int base = (x << 6) + ((cg * 16 + cc * 8) ^ sw);
    uint4 wh, wl;
    wh.x = (u32)hi[cc*8+0] | ((u32)hi[cc*8+1] << 16);
    wh.y = (u32)hi[cc*8+2] | ((u32)hi[cc*8+3] << 16);
    wh.z = (u32)hi[cc*8+4] | ((u32)hi[cc*8+5] << 16);
    wh.w = (u32)hi[cc*8+6] | ((u32)hi[cc*8+7] << 16);
    wl.x = (u32)lo[cc*8+0] | ((u32)lo[cc*8+1] << 16);
    wl.y = (u32)lo[cc*8+2] | ((u32)lo[cc*8+3] << 16);
    wl.z = (u32)lo[cc*8+4] | ((u32)lo[cc*8+5] << 16);
    wl.w = (u32)lo[cc*8+6] | ((u32)lo[cc*8+7] << 16);
    *(uint4*)&dh[base] = wh;
    *(uint4*)&dl[base] = wl;
  }
  if (which && t < 64) {
    float s = 0.f;
#pragma unroll
    for (int c = 0; c < 64; ++c) { float vv = tile[c][t]; s += vv * vv; }
    nk[(b << 12) + (y << 6) + t] = s;
  }
}

// ---------------- kernel 2: 3x3 zero-padded stencil -> kk ----------------
__global__ void kk_kernel(const float* __restrict__ nk, float* __restrict__ kk) {
  int p = blockIdx.x * blockDim.x + threadIdx.x;
  int b = p >> 12, pix = p & 4095;
  int y = pix >> 6, x = pix & 63;
  float s = 0.f;
#pragma unroll
  for (int di = -1; di <= 1; ++di)
#pragma unroll
    for (int dj = -1; dj <= 1; ++dj) {
      int yy = y + di, xx = x + dj;
      if ((unsigned)yy < 64u && (unsigned)xx < 64u)
        s += nk[(b << 12) + (yy << 6) + xx];
    }
  kk[p] = s;
}

// ---------------- kernel 3: hi-only MFMA cost + guarded top-8 ----------------
__launch_bounds__(512, 4)
__global__ void cost_topk_kernel(const u16* __restrict__ qh,
                                 const u16* __restrict__ kh,
                                 const float* __restrict__ kkg,
                                 u32* __restrict__ cand) {
  __shared__ __align__(16) u16 ring[4][4096];        // 32 KB, slot = row & 3
  __shared__ float RbBuf[2 * 66 * 67 + 4];           // 2 bordered S tiles

  int bid = blockIdx.x;
  int b   = bid >> 8;
  int rp  = (bid >> 3) & 31;
  int e8  = bid & 7;
  int q0  = e8 << 3;
  int iy0 = rp << 1;

  int t = threadIdx.x;
  int lane = t & 63;
  int wv = t >> 6;
  int h  = wv >> 2;
  int quad = wv & 3;
  int wr = quad >> 1, wc = quad & 1;
  int l31 = lane & 31, lk8 = (lane >> 5) << 3;
  int apix = (wr << 5) + l31;
  int bpix = (wc << 5) + l31;
  int sx = t & 63, sseg = (t >> 6) & 3, jxs = sseg << 4;
  int iy = iy0 + h;

  const u16* qhb = qh + ((size_t)b << 18);
  const u16* khb = kh + ((size_t)b << 18);

  const bf16x8 z8 = {0,0,0,0,0,0,0,0};
  const uint4 z4 = {0u,0u,0u,0u};

  bf16x8 qa[3][4];
  int swA = (apix & 7) << 3;
#pragma unroll
  for (int d = 0; d < 3; ++d) {
    int qy = iy - 1 + d;
    bool ok = (unsigned)qy < 64u;
    int rb = (qy & 63) << 12;
#pragma unroll
    for (int c4 = 0; c4 < 4; ++c4) {
      bf16x8 vv = *(const bf16x8*)&qhb[rb + (apix << 6) + (((c4 << 4) + lk8) ^ swA)];
      qa[d][c4] = ok ? vv : z8;
    }
  }

  for (int i = t; i < 2 * 66 * 67 + 4; i += 512) RbBuf[i] = 0.f;
#pragma unroll
  for (int d = 0; d < 3; ++d) {
    int r = q0 - 1 + d;
    bool ok = (unsigned)r < 64u;
    uint4 vv = ok ? *(const uint4*)&khb[((r & 63) << 12) + (t << 3)] : z4;
    *(uint4*)&ring[(r + 4) & 3][t << 3] = vv;
  }
  __syncthreads();

  u32 k8a[KTOP], k8b[KTOP];
#pragma unroll
  for (int s = 0; s < KTOP; ++s) { k8a[s] = 0xFFFFFFFFu; k8b[s] = 0xFFFFFFFFu; }

  int swB = (bpix & 7) << 3;
  float* Rh = &RbBuf[h * (66 * 67)];

  for (int jt = 0; jt < 8; ++jt) {
    int jy = q0 + jt;
    int pr = jy + 2;
    bool pok = (jt < 7) && (pr < 64);
    uint4 pf = pok ? *(const uint4*)&khb[((pr & 63) << 12) + (t << 3)] : z4;

    f32x16 acc;
#pragma unroll
    for (int i = 0; i < 16; ++i) acc[i] = 0.f;
#pragma unroll
    for (int d = 0; d < 3; ++d) {
      const u16* rg = ring[(jy - 1 + d) & 3];
#pragma unroll
      for (int c4 = 0; c4 < 4; ++c4) {
        bf16x8 bh = *(const bf16x8*)&rg[(bpix << 6) + (((c4 << 4) + lk8) ^ swB)];
        acc = __builtin_amdgcn_mfma_f32_32x32x16_bf16(qa[d][c4], bh, acc, 0, 0, 0);
      }
    }
    __syncthreads();

#pragma unroll
    for (int r = 0; r < 16; ++r) {
      int row = (wr << 5) + (r & 3) + ((r >> 2) << 3) + ((lane >> 5) << 2);
      Rh[(row + 1) * 67 + (wc << 5) + l31 + 1] = acc[r];
    }
    if (jt < 7) *(uint4*)&ring[pr & 3][t << 3] = pf;
    __syncthreads();

    float a16[16];
    {
      const float* rm = &Rh[sx * 67 + jxs];
      const float* rc = &Rh[(sx + 1) * 67 + jxs];
      const float* rq = &Rh[(sx + 2) * 67 + jxs];
#pragma unroll
      for (int jj = 0; jj < 16; ++jj)
        a16[jj] = rm[jj] + rc[jj + 1] + rq[jj + 2];
    }
    const float* kkr = kkg + (b << 12) + (jy << 6) + jxs;
    int jbase = (jy << 6) + jxs;
    u32 keys[16];
#pragma unroll
    for (int jj = 0; jj < 16; ++jj) {
      float cost = kkr[jj] - 2.f * a16[jj];
      keys[jj] = (ordenc(cost) & 0xFFFFF000u) | (u32)(jbase + jj);
    }
#pragma unroll
    for (int jj = 0; jj < 16; ++jj) {
      if (jj & 1) { if (__any(keys[jj] < k8b[KTOP - 1])) kins(k8b, keys[jj]); }
      else       { if (__any(keys[jj] < k8a[KTOP - 1])) kins(k8a, keys[jj]); }
    }
  }

#pragma unroll
  for (int s = 0; s < KTOP; ++s) kins(k8a, k8b[s]);

  __syncthreads();
  u32* lbuf = (u32*)ring;
  int qloc = (h << 6) + sx;
#pragma unroll
  for (int s = 0; s < KTOP; ++s) lbuf[(qloc << 5) + (sseg << 3) + s] = k8a[s];
  __syncthreads();
  if (t < 128) {
    u32 m8[KTOP];
#pragma unroll
    for (int s = 0; s < KTOP; ++s) m8[s] = 0xFFFFFFFFu;
    for (int e = 0; e < 32; ++e) {
      u32 x = lbuf[(t << 5) + e];
      if (__any(x < m8[KTOP - 1])) kins(m8, x);
    }
    int qi = ((iy0 + (t >> 6)) << 6) + (t & 63);
    u32* dst = cand + (((size_t)(b << 12) + qi) << 6) + (e8 << 3);
#pragma unroll
    for (int s = 0; s < KTOP; ++s) dst[s] = m8[s];
  }
}

// ---------------- kernel 4 (fused): bitonic merge + exact rescore + softmax + gather ----
// block 1024 = 16 waves; wave = one query. grid 512.
__launch_bounds__(1024)
__global__ void fused_out_kernel(const u16* __restrict__ qh, const u16* __restrict__ ql,
                                 const u16* __restrict__ kh, const u16* __restrict__ kl,
                                 const float* __restrict__ kkg, const u32* __restrict__ cand,
                                 const float* __restrict__ v, const float* __restrict__ vt,
                                 float* __restrict__ out, int use_vt) {
  __shared__ float otile[64 * 17];
  int t = threadIdx.x;
  int wid = t >> 6, lane = t & 63;
  int qi = blockIdx.x * 16 + wid;          // == (b<<12) + qpix
  int b = qi >> 12, qpix = qi & 4095;

  // ---- phase A: 64-lane bitonic sort of this query's 64 candidate keys ----
  u32 key = cand[((size_t)qi << 6) + lane];
#pragma unroll
  for (int kk2 = 2; kk2 <= 64; kk2 <<= 1) {
#pragma unroll
    for (int j2 = kk2 >> 1; j2 > 0; j2 >>= 1) {
      u32 o = (u32)__shfl_xor((int)key, j2);
      bool up = ((lane & kk2) == 0);
      bool lowr = ((lane & j2) == 0);
      u32 mn = key < o ? key : o;
      u32 mx = key < o ? o : key;
      key = (up == lowr) ? mn : mx;
    }
  }
  // lanes 0..7 now hold the 8 smallest keys (ascending, exact: index-tagged)

  // ---- phase B: exact fp32 rescore; slot s = lane>>3, ch group g = lane&7 ----
  int s = lane >> 3, g = lane & 7;
  int j = (u32)__shfl((int)key, s) & 0xFFFu;
  int yi = qpix >> 6, xi = qpix & 63;
  int yj = j >> 6, xj = j & 63;
  const u16* qhb = qh + ((size_t)b << 18);
  const u16* qlb = ql + ((size_t)b << 18);
  const u16* khb = kh + ((size_t)b << 18);
  const u16* klb = kl + ((size_t)b << 18);

  float dot = 0.f;
#pragma unroll
  for (int di = 0; di < 3; ++di) {
    int qy = yi + di - 1, ky = yj + di - 1;
    bool vy = ((unsigned)qy < 64u) && ((unsigned)ky < 64u);
#pragma unroll
    for (int dj = 0; dj < 3; ++dj) {
      int qx = xi + dj - 1, kx = xj + dj - 1;
      bool ok = vy && ((unsigned)qx < 64u) && ((unsigned)kx < 64u);
      int qxc = qx & 63, kxc = kx & 63;
      int qa = ((qy & 63) << 12) + (qxc << 6) + ((g << 3) ^ ((qxc & 7) << 3));
      int ka = ((ky & 63) << 12) + (kxc << 6) + ((g << 3) ^ ((kxc & 7) << 3));
      uint4 aqh = *(const uint4*)&qhb[qa];
      uint4 aql = *(const uint4*)&qlb[qa];
      uint4 akh = *(const uint4*)&khb[ka];
      uint4 akl = *(const uint4*)&klb[ka];
      const u32* wqh = (const u32*)&aqh;
      const u32* wql = (const u32*)&aql;
      const u32* wkh = (const u32*)&akh;
      const u32* wkl = (const u32*)&akl;
      float pacc = 0.f;
#pragma unroll
      for (int e = 0; e < 4; ++e) {
        float q0 = __builtin_bit_cast(float, wqh[e] << 16) +
                   __builtin_bit_cast(float, wql[e] << 16);
        float q1 = __builtin_bit_cast(float, wqh[e] & 0xFFFF0000u) +
                   __builtin_bit_cast(float, wql[e] & 0xFFFF0000u);
        float k0 = __builtin_bit_cast(float, wkh[e] << 16) +
                   __builtin_bit_cast(float, wkl[e] << 16);
        float k1 = __builtin_bit_cast(float, wkh[e] & 0xFFFF0000u) +
                   __builtin_bit_cast(float, wkl[e] & 0xFFFF0000u);
        pacc = fmaf(q0, k0, pacc);
        pacc = fmaf(q1, k1, pacc);
      }
      dot += ok ? pacc : 0.f;
    }
  }
  // reduce over the 8 ch-lanes of the slot group (allreduce)
#pragma unroll
  for (int off = 1; off < 8; off <<= 1) dot += __shfl_xor(dot, off);
  float cost = kkg[(b << 12) + j] - 2.f * dot;

  // ---- phase C: softmax over the 8 slots ----
  float m = cost;
#pragma unroll
  for (int off = 8; off < 64; off <<= 1) m = fminf(m, __shfl_xor(m, off));
  float w = __expf(m - cost);
  float wsum = w;
#pragma unroll
  for (int off = 8; off < 64; off <<= 1) wsum += __shfl_xor(wsum, off);
  w /= wsum;

  // ---- phase D: gather v, channel per lane ----
  float wk2[8]; int jk[8];
#pragma unroll
  for (int ss = 0; ss < 8; ++ss) {
    wk2[ss] = __shfl(w, ss << 3);
    jk[ss]  = __shfl(j, ss << 3);
  }
  float acc = 0.f;
  if (use_vt) {
    const float* vtb = vt + ((size_t)b << 18);
#pragma unroll
    for (int ss = 0; ss < 8; ++ss) acc += wk2[ss] * vtb[(jk[ss] << 6) + lane];
  } else {
    const float* vb = v + ((size_t)b << 18);
#pragma unroll
    for (int ss = 0; ss < 8; ++ss) acc += wk2[ss] * vb[(lane << 12) + jk[ss]];
  }
  otile[lane * 17 + wid] = acc;
  __syncthreads();

  // coalesced-ish write: thread -> (c = t>>4, qq = t&15)
  int c2 = t >> 4, qq = t & 15;
  int pixbase = (blockIdx.x & 255) << 4;
  out[((size_t)b << 18) + (c2 << 12) + pixbase + qq] = otile[c2 * 17 + qq];
}

extern "C" void kernel_launch(void* const* d_in, const int* in_sizes, int n_in,
                              void* d_out, int out_size, void* d_ws, size_t ws_size,
                              hipStream_t stream) {
  const float* q = (const float*)d_in[0];
  const float* k = (const float*)d_in[1];
  const float* v = (const float*)d_in[2];
  float* out = (float*)d_out;

  char* ws = (char*)d_ws;
  u16*   qh   = (u16*)(ws);
  u16*   ql   = (u16*)(ws + (1u << 20));
  u16*   kh   = (u16*)(ws + (2u << 20));
  u16*   kl   = (u16*)(ws + (3u << 20));
  float* nk   = (float*)(ws + (4u << 20));
  float* kkp  = (float*)(ws + (4u << 20) + 32768);
  u32*   cand = (u32*)(ws + (4u << 20) + 65536);
  float* vt   = (float*)(ws + (6u << 20) + 65536);
  size_t need = (8u << 20) + 65536;
  int use_vt = (ws_size >= need) ? 1 : 0;

  prep_kernel<<<use_vt ? 384 : 256, 256, 0, stream>>>(q, k, v, qh, ql, kh, kl, vt, nk);
  kk_kernel<<<32, 256, 0, stream>>>(nk, kkp);
  cost_topk_kernel<<<512, 512, 0, stream>>>(qh, kh, kkp, cand);
  fused_out_kernel<<<512, 1024, 0, stream>>>(qh, ql, kh, kl, kkp, cand, v, vt, out, use_vt);
}